// Round 2
// baseline (1070.716 us; speedup 1.0000x reference)
//
#include <hip/hip_runtime.h>
#include <hip/hip_bf16.h>
#include <stdint.h>

// Problem constants
#define B_   64
#define S_   200
#define H_   128
#define V_   20000
#define M_   12800      // B_*S_
#define NPAD 20224      // 79*256
#define NBN  79         // N blocks of 256
#define NBM  100        // M blocks of 128

// ws offsets (bytes) — total ~17.1 MB
#define WS_A      0u          // A_bf16 [12800][256]        6,553,600 B
#define WS_FCW    6553600u    // fcW_bf16 [20224][256]     10,354,688 B
#define WS_FCB    16908288u   // fc_b padded [20224] f32       80,896 B
#define WS_RSUM   16989184u   // rowsum [12800] f32            51,200 B
#define WS_WTIH   17040384u   // W_ih^T [128][128] f32         65,536 B
// end 17,105,920

// scratch inside the y region of d_out (float offsets) — overwritten by final pass
#define XP_OFF    0
#define HOUT_OFF  2000000
#define PART_OFF  4000000          // [NBN][12800] partial exp-sums (~1.01M floats)
#define OUTPU_OFF 256000000ll      // real output 1 (out_pu)

typedef __attribute__((ext_vector_type(8))) __bf16 bf16x8;
typedef __attribute__((ext_vector_type(4))) float  f32x4;

__device__ __forceinline__ void gll16(const void* g, void* l) {
  __builtin_amdgcn_global_load_lds(
      (const __attribute__((address_space(1))) void*)g,
      (__attribute__((address_space(3))) void*)l, 16, 0, 0);
}

// ---------------- prep kernels ----------------
__global__ void prep_fcw(const float* __restrict__ fcw, __hip_bfloat16* __restrict__ out) {
  int n = blockIdx.x, k = threadIdx.x;               // grid 20224 x 256
  float v = (n < V_) ? fcw[(long)n * 256 + k] : 0.f;
  out[(long)n * 256 + k] = __float2bfloat16(v);
}

__global__ void prep_small(const float* __restrict__ w_ih, const float* __restrict__ fcb,
                           float* __restrict__ wt, float* __restrict__ fcbp) {
  int bid = blockIdx.x, t = threadIdx.x;             // grid 207 x 256
  if (bid < 128) {
    if (t < 128) wt[bid * 128 + t] = w_ih[t * 128 + bid];   // wt[k][j] = W_ih[j][k]
  } else {
    int idx = (bid - 128) * 256 + t;
    if (idx < NPAD) fcbp[idx] = (idx < V_) ? fcb[idx] : -1e30f;
  }
}

// ---------------- K1: x_proj = emb[poi] @ W_ih^T + b_ih + b_hh ----------------
__global__ __launch_bounds__(128)
void xproj_k(const int* __restrict__ poi, const float* __restrict__ emb,
             const float* __restrict__ wt_ih, const float* __restrict__ b_ih,
             const float* __restrict__ b_hh, float* __restrict__ xp) {
  __shared__ float xs[128];
  int m = blockIdx.x, j = threadIdx.x;               // grid 12800 x 128
  xs[j] = emb[(long)poi[m] * 128 + j];
  __syncthreads();
  float acc = b_ih[j] + b_hh[j];
#pragma unroll 8
  for (int k = 0; k < 128; ++k) acc = fmaf(xs[k], wt_ih[k * 128 + j], acc);
  xp[(long)m * 128 + j] = acc;
}

// ---------------- K2: sequential RNN (one block per batch row) ----------------
__global__ __launch_bounds__(128)
void rnn_k(const float* __restrict__ xp, const float* __restrict__ w_hh,
           float* __restrict__ hout) {
  int b = blockIdx.x, j = threadIdx.x;               // grid 64 x 128
  float w[128];
#pragma unroll
  for (int k = 0; k < 128; ++k) w[k] = w_hh[j * 128 + k];   // W_hh row j in regs
  __shared__ float hs[2][128];
  hs[0][j] = 0.f;
  __syncthreads();
  int cur = 0;
  for (int t = 0; t < S_; ++t) {
    float acc = xp[((long)b * S_ + t) * 128 + j];
    const float* hp = hs[cur];
#pragma unroll
    for (int k = 0; k < 128; ++k) acc = fmaf(hp[k], w[k], acc);
    float hn = tanhf(acc);
    hs[cur ^ 1][j] = hn;                 // write other buffer (safe w/o barrier)
    hout[((long)b * S_ + t) * 128 + j] = hn;
    cur ^= 1;
    __syncthreads();
  }
}

// ---------------- K3: decay attention + build out_pu (fp32 out, bf16 A) ----------------
__global__ __launch_bounds__(128)
void attn_k(const float* __restrict__ ts, const float* __restrict__ loc,
            const float* __restrict__ hout, const int* __restrict__ auser,
            const float* __restrict__ userW, float* __restrict__ outpu,
            __hip_bfloat16* __restrict__ Abf) {
  int i = blockIdx.x, b = blockIdx.y, h = threadIdx.x;   // grid (200,64) x 128
  __shared__ float wl[128];
  const float OMEGA = 7.27220521664304e-05f;             // 2*pi/86400
  float ti = ts[b * S_ + i];
  float lx = loc[(b * S_ + i) * 2 + 0];
  float ly = loc[(b * S_ + i) * 2 + 1];
  float acc = 0.f, sw = 0.f;
  for (int jc = 0; jc <= i; jc += 128) {
    int j = jc + h;
    float wj = 0.f;
    if (j <= i) {
      float dt = fmaxf(ti - ts[b * S_ + j], 0.f);
      float a = (cosf(dt * OMEGA) + 1.f) * 0.5f * expf(-dt * 0.01f);
      float dx = lx - loc[(b * S_ + j) * 2 + 0];
      float dy = ly - loc[(b * S_ + j) * 2 + 1];
      float dn = sqrtf(dx * dx + dy * dy);
      wj = a * expf(-dn * 100.f) + 1e-10f;
    }
    __syncthreads();
    wl[h] = wj;
    __syncthreads();
    int lim = min(128, i - jc + 1);
    const float* hb = hout + ((long)b * S_ + jc) * 128 + h;
    for (int jj = 0; jj < lim; ++jj) {
      float wv = wl[jj];
      acc = fmaf(wv, hb[(long)jj * 128], acc);
      sw += wv;
    }
  }
  float ow = acc / fmaxf(sw, 1e-10f);
  long m = (long)b * S_ + i;
  float pu = userW[(long)auser[b] * 128 + h];
  outpu[m * 256 + h]       = ow;
  outpu[m * 256 + 128 + h] = pu;
  Abf[m * 256 + h]         = __float2bfloat16(ow);
  Abf[m * 256 + 128 + h]   = __float2bfloat16(pu);
}

// ---------------- K4/K5: FC GEMM, 128x256 tile, 2-phase dbuf prefetch ----------------
// PASS 0: per-row partial sum of exp(logit) -> part[bn][row]
// PASS 1: y[row][col] = exp(logit) / rowsum[row]
template <int PASS>
__global__ __launch_bounds__(512)
void gemm_fc(const __hip_bfloat16* __restrict__ A,    // [12800][256]
             const __hip_bfloat16* __restrict__ Bw,   // [20224][256]
             const float* __restrict__ fcb,           // [20224], pad = -1e30
             const float* __restrict__ rowsum,        // [12800] (PASS 1)
             float* __restrict__ part,                 // [NBN][12800] (PASS 0)
             float* __restrict__ y) {                  // [12800][20000] (PASS 1)
  __shared__ __align__(16) __hip_bfloat16 As[2][128 * 32];   // 2 x 8 KB
  __shared__ __align__(16) __hip_bfloat16 Bs[2][256 * 32];   // 2 x 16 KB
  __shared__ float rsum4[4][128];

  const int tid  = threadIdx.x;
  const int lane = tid & 63;
  const int wid  = tid >> 6;          // 0..7
  const int wr = wid >> 2, wc = wid & 3;   // 2 x 4 wave grid
  const int g = lane >> 4, lr = lane & 15;
  const int bn = blockIdx.x, bm = blockIdx.y;
  const long brow = (long)bm * 128, bcol = (long)bn * 256;

  f32x4 acc[4][4];
#pragma unroll
  for (int mi = 0; mi < 4; ++mi)
#pragma unroll
    for (int ni = 0; ni < 4; ++ni) acc[mi][ni] = (f32x4)(0.f);

  const char* Ab = (const char*)A + brow * 512;   // row stride 256*2B
  const char* Bb = (const char*)Bw + bcol * 512;
  const int rA = tid >> 2;             // 0..127
  const int oA = (tid & 3) * 16;       // byte offset within 64B K-row

  // prologue: stage K-tile 0 into buffer 0
  {
    gll16(Ab + (long)rA * 512 + oA,              (char*)As[0] + tid * 16);
    gll16(Bb + (long)rA * 512 + oA,              (char*)Bs[0] + tid * 16);
    gll16(Bb + (long)(rA + 128) * 512 + oA,      (char*)Bs[0] + (tid + 512) * 16);
  }
  __syncthreads();

  int cur = 0;
  for (int kk = 0; kk < 8; ++kk) {
    // LDS -> register fragments for current K-tile
    bf16x8 af[4], bfr[4];
#pragma unroll
    for (int mi = 0; mi < 4; ++mi)
      af[mi] = *(const bf16x8*)((const char*)As[cur] + (wr * 64 + mi * 16 + lr) * 64 + g * 16);
#pragma unroll
    for (int ni = 0; ni < 4; ++ni)
      bfr[ni] = *(const bf16x8*)((const char*)Bs[cur] + (wc * 64 + ni * 16 + lr) * 64 + g * 16);

    // issue next K-tile's loads into the other buffer (hidden under MFMA)
    if (kk < 7) {
      const int kb = (kk + 1) * 64;   // 32 bf16 = 64 bytes of K
      gll16(Ab + (long)rA * 512 + kb + oA,         (char*)As[cur ^ 1] + tid * 16);
      gll16(Bb + (long)rA * 512 + kb + oA,         (char*)Bs[cur ^ 1] + tid * 16);
      gll16(Bb + (long)(rA + 128) * 512 + kb + oA, (char*)Bs[cur ^ 1] + (tid + 512) * 16);
    }

#pragma unroll
    for (int mi = 0; mi < 4; ++mi)
#pragma unroll
      for (int ni = 0; ni < 4; ++ni)
        acc[mi][ni] = __builtin_amdgcn_mfma_f32_16x16x32_bf16(af[mi], bfr[ni], acc[mi][ni], 0, 0, 0);

    __syncthreads();   // drains vmcnt (prefetch landed during MFMA) + joins waves
    cur ^= 1;
  }

  float fb[4];
#pragma unroll
  for (int ni = 0; ni < 4; ++ni) fb[ni] = fcb[bcol + wc * 64 + ni * 16 + lr];

  if (PASS == 0) {
#pragma unroll
    for (int mi = 0; mi < 4; ++mi) {
#pragma unroll
      for (int r = 0; r < 4; ++r) {
        float s = 0.f;
#pragma unroll
        for (int ni = 0; ni < 4; ++ni) s += __expf(acc[mi][ni][r] + fb[ni]);
#pragma unroll
        for (int off = 1; off < 16; off <<= 1) s += __shfl_xor(s, off);
        if (lr == 0) rsum4[wc][wr * 64 + mi * 16 + g * 4 + r] = s;
      }
    }
    __syncthreads();
    if (tid < 128)
      part[(long)bn * M_ + brow + tid] =
          rsum4[0][tid] + rsum4[1][tid] + rsum4[2][tid] + rsum4[3][tid];
  } else {
#pragma unroll
    for (int mi = 0; mi < 4; ++mi) {
#pragma unroll
      for (int r = 0; r < 4; ++r) {
        long row = brow + wr * 64 + mi * 16 + g * 4 + r;
        float inv = 1.0f / rowsum[row];
        long base = row * (long)V_;
#pragma unroll
        for (int ni = 0; ni < 4; ++ni) {
          int col = (int)bcol + wc * 64 + ni * 16 + lr;
          if (col < V_) y[base + col] = __expf(acc[mi][ni][r] + fb[ni]) * inv;
        }
      }
    }
  }
}

__global__ void reduce_rows(const float* __restrict__ part, float* __restrict__ rowsum) {
  int m = blockIdx.x * 256 + threadIdx.x;            // grid 50 x 256
  if (m < M_) {
    float s = 0.f;
    for (int bn = 0; bn < NBN; ++bn) s += part[(long)bn * M_ + m];
    rowsum[m] = fmaxf(s, 1e-30f);
  }
}

// ---------------- launcher ----------------
extern "C" void kernel_launch(void* const* d_in, const int* in_sizes, int n_in,
                              void* d_out, int out_size, void* d_ws, size_t ws_size,
                              hipStream_t stream) {
  const int*   poi   = (const int*)d_in[0];
  // d_in[1] = lengths (all == S, unused)
  const float* ts    = (const float*)d_in[2];
  const float* loc   = (const float*)d_in[3];
  const int*   auser = (const int*)d_in[4];
  const float* embW  = (const float*)d_in[5];
  const float* userW = (const float*)d_in[6];
  const float* w_ih  = (const float*)d_in[7];
  const float* w_hh  = (const float*)d_in[8];
  const float* b_ih  = (const float*)d_in[9];
  const float* b_hh  = (const float*)d_in[10];
  const float* fcW   = (const float*)d_in[11];
  const float* fcb   = (const float*)d_in[12];

  float* out = (float*)d_out;
  char*  ws  = (char*)d_ws;
  __hip_bfloat16* Abf    = (__hip_bfloat16*)(ws + WS_A);
  __hip_bfloat16* fcWb   = (__hip_bfloat16*)(ws + WS_FCW);
  float*          fcbp   = (float*)(ws + WS_FCB);
  float*          rowsum = (float*)(ws + WS_RSUM);
  float*          wt_ih  = (float*)(ws + WS_WTIH);

  float* xp    = out + XP_OFF;     // scratch inside y region (overwritten by pass 1)
  float* hout  = out + HOUT_OFF;
  float* part  = out + PART_OFF;
  float* outpu = out + OUTPU_OFF;  // real output 1

  prep_fcw<<<dim3(NPAD), dim3(256), 0, stream>>>(fcW, fcWb);
  prep_small<<<dim3(207), dim3(256), 0, stream>>>(w_ih, fcb, wt_ih, fcbp);
  xproj_k<<<dim3(M_), dim3(128), 0, stream>>>(poi, embW, wt_ih, b_ih, b_hh, xp);
  rnn_k<<<dim3(B_), dim3(128), 0, stream>>>(xp, w_hh, hout);
  attn_k<<<dim3(S_, B_), dim3(128), 0, stream>>>(ts, loc, hout, auser, userW, outpu, Abf);
  gemm_fc<0><<<dim3(NBN, NBM), dim3(512), 0, stream>>>(Abf, fcWb, fcbp, nullptr, part, nullptr);
  reduce_rows<<<dim3(50), dim3(256), 0, stream>>>(part, rowsum);
  gemm_fc<1><<<dim3(NBN, NBM), dim3(512), 0, stream>>>(Abf, fcWb, fcbp, rowsum, nullptr, out);
}

// Round 3
// 990.497 us; speedup vs baseline: 1.0810x; 1.0810x over previous
//
#include <hip/hip_runtime.h>
#include <hip/hip_bf16.h>
#include <stdint.h>

// Problem constants
#define B_   64
#define S_   200
#define H_   128
#define V_   20000
#define M_   12800      // B_*S_
#define NPAD 20224      // 79*256
#define NBN  79         // N blocks of 256
#define NBM  50         // M blocks of 256
#define NWG  3950       // NBN*NBM

// ws offsets (bytes) — total ~17.1 MB
#define WS_A      0u          // A_bf16 [12800][256]        6,553,600 B
#define WS_FCW    6553600u    // fcW_bf16 [20224][256]     10,354,688 B
#define WS_FCB    16908288u   // fc_b padded [20224] f32       80,896 B
#define WS_RSUM   16989184u   // rowsum [12800] f32            51,200 B
#define WS_WTIH   17040384u   // W_ih^T [128][128] f32         65,536 B
// end 17,105,920

// scratch inside the y region of d_out (float offsets) — overwritten by final pass
#define XP_OFF    0
#define HOUT_OFF  2000000
#define PART_OFF  4000000          // [NBN][12800] partial exp-sums
#define OUTPU_OFF 256000000ll      // real output 1 (out_pu)

typedef __attribute__((ext_vector_type(8))) __bf16 bf16x8;
typedef __attribute__((ext_vector_type(4))) float  f32x4;

__device__ __forceinline__ void gll16(const void* g, void* l) {
  __builtin_amdgcn_global_load_lds(
      (const __attribute__((address_space(1))) void*)g,
      (__attribute__((address_space(3))) void*)l, 16, 0, 0);
}

// ---------------- prep kernels ----------------
__global__ void prep_fcw(const float* __restrict__ fcw, __hip_bfloat16* __restrict__ out) {
  int n = blockIdx.x, k = threadIdx.x;               // grid 20224 x 256
  float v = (n < V_) ? fcw[(long)n * 256 + k] : 0.f;
  out[(long)n * 256 + k] = __float2bfloat16(v);
}

__global__ void prep_small(const float* __restrict__ w_ih, const float* __restrict__ fcb,
                           float* __restrict__ wt, float* __restrict__ fcbp) {
  int bid = blockIdx.x, t = threadIdx.x;             // grid 207 x 256
  if (bid < 128) {
    if (t < 128) wt[bid * 128 + t] = w_ih[t * 128 + bid];   // wt[k][j] = W_ih[j][k]
  } else {
    int idx = (bid - 128) * 256 + t;
    if (idx < NPAD) fcbp[idx] = (idx < V_) ? fcb[idx] : -1e30f;
  }
}

// ---------------- K1: x_proj = emb[poi] @ W_ih^T + b_ih + b_hh ----------------
__global__ __launch_bounds__(128)
void xproj_k(const int* __restrict__ poi, const float* __restrict__ emb,
             const float* __restrict__ wt_ih, const float* __restrict__ b_ih,
             const float* __restrict__ b_hh, float* __restrict__ xp) {
  __shared__ float xs[128];
  int m = blockIdx.x, j = threadIdx.x;               // grid 12800 x 128
  xs[j] = emb[(long)poi[m] * 128 + j];
  __syncthreads();
  float acc = b_ih[j] + b_hh[j];
#pragma unroll 8
  for (int k = 0; k < 128; ++k) acc = fmaf(xs[k], wt_ih[k * 128 + j], acc);
  xp[(long)m * 128 + j] = acc;
}

// ---------------- K2: sequential RNN (one block per batch row) ----------------
__global__ __launch_bounds__(128)
void rnn_k(const float* __restrict__ xp, const float* __restrict__ w_hh,
           float* __restrict__ hout) {
  int b = blockIdx.x, j = threadIdx.x;               // grid 64 x 128
  float w[128];
#pragma unroll
  for (int k = 0; k < 128; ++k) w[k] = w_hh[j * 128 + k];   // W_hh row j in regs
  __shared__ float hs[2][128];
  hs[0][j] = 0.f;
  __syncthreads();
  int cur = 0;
  for (int t = 0; t < S_; ++t) {
    float acc = xp[((long)b * S_ + t) * 128 + j];
    const float* hp = hs[cur];
#pragma unroll
    for (int k = 0; k < 128; ++k) acc = fmaf(hp[k], w[k], acc);
    float hn = tanhf(acc);
    hs[cur ^ 1][j] = hn;                 // write other buffer (safe w/o barrier)
    hout[((long)b * S_ + t) * 128 + j] = hn;
    cur ^= 1;
    __syncthreads();
  }
}

// ---------------- K3: decay attention + build out_pu (fp32 out, bf16 A) ----------------
__global__ __launch_bounds__(128)
void attn_k(const float* __restrict__ ts, const float* __restrict__ loc,
            const float* __restrict__ hout, const int* __restrict__ auser,
            const float* __restrict__ userW, float* __restrict__ outpu,
            __hip_bfloat16* __restrict__ Abf) {
  int i = blockIdx.x, b = blockIdx.y, h = threadIdx.x;   // grid (200,64) x 128
  __shared__ float wl[128];
  const float OMEGA = 7.27220521664304e-05f;             // 2*pi/86400
  float ti = ts[b * S_ + i];
  float lx = loc[(b * S_ + i) * 2 + 0];
  float ly = loc[(b * S_ + i) * 2 + 1];
  float acc = 0.f, sw = 0.f;
  for (int jc = 0; jc <= i; jc += 128) {
    int j = jc + h;
    float wj = 0.f;
    if (j <= i) {
      float dt = fmaxf(ti - ts[b * S_ + j], 0.f);
      float a = (cosf(dt * OMEGA) + 1.f) * 0.5f * expf(-dt * 0.01f);
      float dx = lx - loc[(b * S_ + j) * 2 + 0];
      float dy = ly - loc[(b * S_ + j) * 2 + 1];
      float dn = sqrtf(dx * dx + dy * dy);
      wj = a * expf(-dn * 100.f) + 1e-10f;
    }
    __syncthreads();
    wl[h] = wj;
    __syncthreads();
    int lim = min(128, i - jc + 1);
    const float* hb = hout + ((long)b * S_ + jc) * 128 + h;
    for (int jj = 0; jj < lim; ++jj) {
      float wv = wl[jj];
      acc = fmaf(wv, hb[(long)jj * 128], acc);
      sw += wv;
    }
  }
  float ow = acc / fmaxf(sw, 1e-10f);
  long m = (long)b * S_ + i;
  float pu = userW[(long)auser[b] * 128 + h];
  outpu[m * 256 + h]       = ow;
  outpu[m * 256 + 128 + h] = pu;
  Abf[m * 256 + h]         = __float2bfloat16(ow);
  Abf[m * 256 + 128 + h]   = __float2bfloat16(pu);
}

// ---------------- K4/K5: FC GEMM, 256x256 tile, m97 2-barrier loop, XCD swizzle ----------------
// PASS 0: per-row partial sum of exp(logit) -> part[bn][row]
// PASS 1: y[row][col] = exp(logit) / rowsum[row]
template <int PASS>
__global__ __launch_bounds__(512)
void gemm_fc(const __hip_bfloat16* __restrict__ A,    // [12800][256]
             const __hip_bfloat16* __restrict__ Bw,   // [20224][256]
             const float* __restrict__ fcb,           // [20224], pad = -1e30
             const float* __restrict__ rowsum,        // [12800] (PASS 1)
             float* __restrict__ part,                 // [NBN][12800] (PASS 0)
             float* __restrict__ y) {                  // [12800][20000] (PASS 1)
  __shared__ __align__(16) __hip_bfloat16 As[256 * 32];   // 16 KB
  __shared__ __align__(16) __hip_bfloat16 Bs[256 * 32];   // 16 KB
  __shared__ float rsum4[4][256];                          // 4 KB

  const int tid  = threadIdx.x;
  const int lane = tid & 63;
  const int wid  = tid >> 6;               // 0..7
  const int wr = wid >> 2, wc = wid & 3;   // 2 x 4 wave grid, wave tile 128x64
  const int g = lane >> 4, lr = lane & 15;

  // bijective XCD swizzle (m204): each XCD gets ~10 contiguous N-panels x all M
  {
  }
  const int orig = blockIdx.x;
  const int qq = NWG >> 3, rr = NWG & 7;   // 493, 6
  const int xcd = orig & 7, lix = orig >> 3;
  const int nid = (xcd < rr ? xcd * (qq + 1) : rr * (qq + 1) + (xcd - rr) * qq) + lix;
  const int bn = nid / NBM, bm = nid % NBM;
  const long brow = (long)bm * 256, bcol = (long)bn * 256;

  f32x4 acc[8][4];
#pragma unroll
  for (int mi = 0; mi < 8; ++mi)
#pragma unroll
    for (int ni = 0; ni < 4; ++ni) acc[mi][ni] = (f32x4)(0.f);

  const char* Ab = (const char*)A + brow * 512;   // row stride 256*2B
  const char* Bb = (const char*)Bw + bcol * 512;
  char* AsB = (char*)As;
  char* BsB = (char*)Bs;
  const int t1 = tid + 512;
  const int r0 = tid >> 2, o0 = (tid & 3) * 16;   // rows 0..127
  const int r1 = t1 >> 2,  o1 = (t1 & 3) * 16;    // rows 128..255

  for (int kk = 0; kk < 8; ++kk) {
    __syncthreads();
    const int kb = kk * 64;                        // 32 bf16 = 64 bytes of K
    gll16(Ab + (long)r0 * 512 + kb + o0, AsB + tid * 16);
    gll16(Ab + (long)r1 * 512 + kb + o1, AsB + t1 * 16);
    gll16(Bb + (long)r0 * 512 + kb + o0, BsB + tid * 16);
    gll16(Bb + (long)r1 * 512 + kb + o1, BsB + t1 * 16);
    __syncthreads();
    bf16x8 af[8], bfr[4];
#pragma unroll
    for (int mi = 0; mi < 8; ++mi)
      af[mi] = *(const bf16x8*)(AsB + (wr * 128 + mi * 16 + lr) * 64 + g * 16);
#pragma unroll
    for (int ni = 0; ni < 4; ++ni)
      bfr[ni] = *(const bf16x8*)(BsB + (wc * 64 + ni * 16 + lr) * 64 + g * 16);
#pragma unroll
    for (int mi = 0; mi < 8; ++mi)
#pragma unroll
      for (int ni = 0; ni < 4; ++ni)
        acc[mi][ni] = __builtin_amdgcn_mfma_f32_16x16x32_bf16(af[mi], bfr[ni], acc[mi][ni], 0, 0, 0);
  }

  float fb[4];
#pragma unroll
  for (int ni = 0; ni < 4; ++ni) fb[ni] = fcb[bcol + wc * 64 + ni * 16 + lr];

  if (PASS == 0) {
#pragma unroll
    for (int mi = 0; mi < 8; ++mi) {
#pragma unroll
      for (int r = 0; r < 4; ++r) {
        float s = 0.f;
#pragma unroll
        for (int ni = 0; ni < 4; ++ni) s += __expf(acc[mi][ni][r] + fb[ni]);
#pragma unroll
        for (int off = 1; off < 16; off <<= 1) s += __shfl_xor(s, off);
        if (lr == 0) rsum4[wc][wr * 128 + mi * 16 + g * 4 + r] = s;
      }
    }
    __syncthreads();
    if (tid < 256)
      part[(long)bn * M_ + brow + tid] =
          rsum4[0][tid] + rsum4[1][tid] + rsum4[2][tid] + rsum4[3][tid];
  } else {
#pragma unroll
    for (int mi = 0; mi < 8; ++mi) {
#pragma unroll
      for (int r = 0; r < 4; ++r) {
        long row = brow + wr * 128 + mi * 16 + g * 4 + r;
        float inv = 1.0f / rowsum[row];
        long base = row * (long)V_;
#pragma unroll
        for (int ni = 0; ni < 4; ++ni) {
          int col = (int)bcol + wc * 64 + ni * 16 + lr;
          if (col < V_) y[base + col] = __expf(acc[mi][ni][r] + fb[ni]) * inv;
        }
      }
    }
  }
}

__global__ void reduce_rows(const float* __restrict__ part, float* __restrict__ rowsum) {
  int m = blockIdx.x * 256 + threadIdx.x;            // grid 50 x 256
  if (m < M_) {
    float s = 0.f;
    for (int bn = 0; bn < NBN; ++bn) s += part[(long)bn * M_ + m];
    rowsum[m] = fmaxf(s, 1e-30f);
  }
}

// ---------------- launcher ----------------
extern "C" void kernel_launch(void* const* d_in, const int* in_sizes, int n_in,
                              void* d_out, int out_size, void* d_ws, size_t ws_size,
                              hipStream_t stream) {
  const int*   poi   = (const int*)d_in[0];
  // d_in[1] = lengths (all == S, unused)
  const float* ts    = (const float*)d_in[2];
  const float* loc   = (const float*)d_in[3];
  const int*   auser = (const int*)d_in[4];
  const float* embW  = (const float*)d_in[5];
  const float* userW = (const float*)d_in[6];
  const float* w_ih  = (const float*)d_in[7];
  const float* w_hh  = (const float*)d_in[8];
  const float* b_ih  = (const float*)d_in[9];
  const float* b_hh  = (const float*)d_in[10];
  const float* fcW   = (const float*)d_in[11];
  const float* fcb   = (const float*)d_in[12];

  float* out = (float*)d_out;
  char*  ws  = (char*)d_ws;
  __hip_bfloat16* Abf    = (__hip_bfloat16*)(ws + WS_A);
  __hip_bfloat16* fcWb   = (__hip_bfloat16*)(ws + WS_FCW);
  float*          fcbp   = (float*)(ws + WS_FCB);
  float*          rowsum = (float*)(ws + WS_RSUM);
  float*          wt_ih  = (float*)(ws + WS_WTIH);

  float* xp    = out + XP_OFF;     // scratch inside y region (overwritten by pass 1)
  float* hout  = out + HOUT_OFF;
  float* part  = out + PART_OFF;
  float* outpu = out + OUTPU_OFF;  // real output 1

  prep_fcw<<<dim3(NPAD), dim3(256), 0, stream>>>(fcW, fcWb);
  prep_small<<<dim3(207), dim3(256), 0, stream>>>(w_ih, fcb, wt_ih, fcbp);
  xproj_k<<<dim3(M_), dim3(128), 0, stream>>>(poi, embW, wt_ih, b_ih, b_hh, xp);
  rnn_k<<<dim3(B_), dim3(128), 0, stream>>>(xp, w_hh, hout);
  attn_k<<<dim3(S_, B_), dim3(128), 0, stream>>>(ts, loc, hout, auser, userW, outpu, Abf);
  gemm_fc<0><<<dim3(NWG), dim3(512), 0, stream>>>(Abf, fcWb, fcbp, nullptr, part, nullptr);
  reduce_rows<<<dim3(50), dim3(256), 0, stream>>>(part, rowsum);
  gemm_fc<1><<<dim3(NWG), dim3(512), 0, stream>>>(Abf, fcWb, fcbp, rowsum, nullptr, out);
}

// Round 4
// 888.164 us; speedup vs baseline: 1.2055x; 1.1152x over previous
//
#include <hip/hip_runtime.h>
#include <hip/hip_bf16.h>
#include <stdint.h>

// Problem constants
#define B_   64
#define S_   200
#define H_   128
#define V_   20000
#define M_   12800      // B_*S_
#define NPAD 20224      // 158*128
#define NBN  158        // N blocks of 128
#define NBM  100        // M blocks of 128
#define NWG2 15800      // NBN*NBM (== 8*1975)

// ws offsets (bytes) — total ~13.7 MB
#define WS_A      0u          // A1_bf16 [12800][128]      3,276,800 B
#define WS_FCW    3276800u    // W1_bf16 [20224][128]      5,177,344 B
#define WS_U      8454144u    // U [64][20224] f32         5,177,344 B
#define WS_RSUM   13631488u   // rowsum [12800] f32           51,200 B
#define WS_WTIH   13682688u   // W_ih^T [128][128] f32        65,536 B
// end 13,748,224

// scratch inside the y region of d_out (float offsets) — overwritten by final pass
#define XP_OFF    0
#define HOUT_OFF  2000000
#define PART_OFF  4000000          // [NBN][12800] partial exp-sums (2.02M floats)
#define OUTPU_OFF 256000000ll      // real output 1 (out_pu)

typedef __attribute__((ext_vector_type(8))) __bf16 bf16x8;
typedef __attribute__((ext_vector_type(4))) float  f32x4;

__device__ __forceinline__ void gll16(const void* g, void* l) {
  __builtin_amdgcn_global_load_lds(
      (const __attribute__((address_space(1))) void*)g,
      (__attribute__((address_space(3))) void*)l, 16, 0, 0);
}

// ---------------- prep: W1 bf16 (first 128 cols of fc_W) ----------------
__global__ __launch_bounds__(256)
void prep_w1(const float* __restrict__ fcw, __hip_bfloat16* __restrict__ w1) {
  int t = threadIdx.x;
  int row = blockIdx.x * 2 + (t >> 7);          // grid 10112 x 256
  int col = t & 127;
  float v = (row < V_) ? fcw[(long)row * 256 + col] : 0.f;
  w1[(long)row * 128 + col] = __float2bfloat16(v);
}

// ---------------- prep: W_ih transpose ----------------
__global__ __launch_bounds__(128)
void prep_wt(const float* __restrict__ w_ih, float* __restrict__ wt) {
  int bid = blockIdx.x, t = threadIdx.x;        // grid 128 x 128
  wt[bid * 128 + t] = w_ih[t * 128 + bid];      // wt[k][j] = W_ih[j][k]
}

// ---------------- U table: U[b][c] = p_u(b) . fcW[c,128:256] + fcb[c] ----------------
__global__ __launch_bounds__(256)
void user_k(const int* __restrict__ auser, const float* __restrict__ userW,
            const float* __restrict__ fcW, const float* __restrict__ fcb,
            float* __restrict__ U) {
  __shared__ float uw[8][128];
  int t = threadIdx.x;
  int c = blockIdx.x * 256 + t;                 // grid (79, 8)
  int b0 = blockIdx.y * 8;
  for (int i = t; i < 8 * 128; i += 256) {
    int bb = i >> 7, kk = i & 127;
    uw[bb][kk] = userW[(long)auser[b0 + bb] * 128 + kk];
  }
  __syncthreads();
  float acc[8];
#pragma unroll
  for (int bb = 0; bb < 8; ++bb) acc[bb] = 0.f;
  if (c < V_) {
    const float* w2 = fcW + (long)c * 256 + 128;
#pragma unroll 4
    for (int k = 0; k < 128; k += 4) {
      float4 wv = *(const float4*)(w2 + k);
#pragma unroll
      for (int bb = 0; bb < 8; ++bb) {
        acc[bb] = fmaf(wv.x, uw[bb][k], acc[bb]);
        acc[bb] = fmaf(wv.y, uw[bb][k + 1], acc[bb]);
        acc[bb] = fmaf(wv.z, uw[bb][k + 2], acc[bb]);
        acc[bb] = fmaf(wv.w, uw[bb][k + 3], acc[bb]);
      }
    }
    float base = fcb[c];
#pragma unroll
    for (int bb = 0; bb < 8; ++bb)
      U[(long)(b0 + bb) * NPAD + c] = base + acc[bb];
  } else {
#pragma unroll
    for (int bb = 0; bb < 8; ++bb)
      U[(long)(b0 + bb) * NPAD + c] = -1e30f;    // pad cols: exp -> 0
  }
}

// ---------------- K1: x_proj = emb[poi] @ W_ih^T + b_ih + b_hh ----------------
__global__ __launch_bounds__(128)
void xproj_k(const int* __restrict__ poi, const float* __restrict__ emb,
             const float* __restrict__ wt_ih, const float* __restrict__ b_ih,
             const float* __restrict__ b_hh, float* __restrict__ xp) {
  __shared__ float xs[128];
  int m = blockIdx.x, j = threadIdx.x;               // grid 12800 x 128
  xs[j] = emb[(long)poi[m] * 128 + j];
  __syncthreads();
  float acc = b_ih[j] + b_hh[j];
#pragma unroll 8
  for (int k = 0; k < 128; ++k) acc = fmaf(xs[k], wt_ih[k * 128 + j], acc);
  xp[(long)m * 128 + j] = acc;
}

// ---------------- K2: sequential RNN (4-way split dep chain) ----------------
__global__ __launch_bounds__(128)
void rnn_k(const float* __restrict__ xp, const float* __restrict__ w_hh,
           float* __restrict__ hout) {
  int b = blockIdx.x, j = threadIdx.x;               // grid 64 x 128
  float w[128];
#pragma unroll
  for (int k = 0; k < 128; ++k) w[k] = w_hh[j * 128 + k];
  __shared__ float hs[2][128];
  hs[0][j] = 0.f;
  __syncthreads();
  int cur = 0;
  for (int t = 0; t < S_; ++t) {
    float x0 = xp[((long)b * S_ + t) * 128 + j];
    const float* hp = hs[cur];
    float a0 = 0.f, a1 = 0.f, a2 = 0.f, a3 = 0.f;
#pragma unroll
    for (int k = 0; k < 32; ++k) {
      a0 = fmaf(hp[k],      w[k],      a0);
      a1 = fmaf(hp[k + 32], w[k + 32], a1);
      a2 = fmaf(hp[k + 64], w[k + 64], a2);
      a3 = fmaf(hp[k + 96], w[k + 96], a3);
    }
    float hn = tanhf(x0 + ((a0 + a1) + (a2 + a3)));
    hs[cur ^ 1][j] = hn;
    hout[((long)b * S_ + t) * 128 + j] = hn;
    cur ^= 1;
    __syncthreads();
  }
}

// ---------------- K3: decay attention + out_pu + A1 bf16 ----------------
__global__ __launch_bounds__(128)
void attn_k(const float* __restrict__ ts, const float* __restrict__ loc,
            const float* __restrict__ hout, const int* __restrict__ auser,
            const float* __restrict__ userW, float* __restrict__ outpu,
            __hip_bfloat16* __restrict__ Abf) {
  int i = blockIdx.x, b = blockIdx.y, h = threadIdx.x;   // grid (200,64) x 128
  __shared__ float wl[128];
  const float OMEGA = 7.27220521664304e-05f;             // 2*pi/86400
  float ti = ts[b * S_ + i];
  float lx = loc[(b * S_ + i) * 2 + 0];
  float ly = loc[(b * S_ + i) * 2 + 1];
  float acc = 0.f, sw = 0.f;
  for (int jc = 0; jc <= i; jc += 128) {
    int j = jc + h;
    float wj = 0.f;
    if (j <= i) {
      float dt = fmaxf(ti - ts[b * S_ + j], 0.f);
      float a = (cosf(dt * OMEGA) + 1.f) * 0.5f * expf(-dt * 0.01f);
      float dx = lx - loc[(b * S_ + j) * 2 + 0];
      float dy = ly - loc[(b * S_ + j) * 2 + 1];
      float dn = sqrtf(dx * dx + dy * dy);
      wj = a * expf(-dn * 100.f) + 1e-10f;
    }
    __syncthreads();
    wl[h] = wj;
    __syncthreads();
    int lim = min(128, i - jc + 1);
    const float* hb = hout + ((long)b * S_ + jc) * 128 + h;
    for (int jj = 0; jj < lim; ++jj) {
      float wv = wl[jj];
      acc = fmaf(wv, hb[(long)jj * 128], acc);
      sw += wv;
    }
  }
  float ow = acc / fmaxf(sw, 1e-10f);
  long m = (long)b * S_ + i;
  float pu = userW[(long)auser[b] * 128 + h];
  outpu[m * 256 + h]       = ow;
  outpu[m * 256 + 128 + h] = pu;
  Abf[m * 128 + h]         = __float2bfloat16(ow);   // only out_w half feeds GEMM
}

// ---------------- K4/K5: FC GEMM, K=128, 128x128 tile (m97/r1 structure) ----------------
// logit(r,c) = acc(r,c) + U[r/200][c];  PASS0: rowsum partials;  PASS1: y = exp/rowsum
template <int PASS>
__global__ __launch_bounds__(256)
void gemm_fc(const __hip_bfloat16* __restrict__ A,    // [12800][128]
             const __hip_bfloat16* __restrict__ Bw,   // [20224][128]
             const float* __restrict__ Ut,            // [64][20224]
             const float* __restrict__ rowsum,        // [12800] (PASS 1)
             float* __restrict__ part,                 // [NBN][12800] (PASS 0)
             float* __restrict__ y) {                  // [12800][20000] (PASS 1)
  __shared__ __align__(16) __hip_bfloat16 As[128 * 32];
  __shared__ __align__(16) __hip_bfloat16 Bs[128 * 32];
  __shared__ float rsum2[2][128];

  const int tid  = threadIdx.x;
  const int lane = tid & 63;
  const int wid  = tid >> 6;
  const int wr = wid >> 1, wc = wid & 1;
  const int g = lane >> 4, lr = lane & 15;

  // bijective XCD swizzle: 15800 = 8*1975; each XCD gets ~20 contiguous N-panels
  const int orig = blockIdx.x;
  const int nid = (orig & 7) * (NWG2 / 8) + (orig >> 3);
  const int bn = nid / NBM, bm = nid % NBM;
  const long brow = (long)bm * 128, bcol = (long)bn * 128;

  f32x4 acc[4][4];
#pragma unroll
  for (int mi = 0; mi < 4; ++mi)
#pragma unroll
    for (int ni = 0; ni < 4; ++ni) acc[mi][ni] = (f32x4)(0.f);

  const char* Ab = (const char*)A + brow * 256;   // row stride 128*2B
  const char* Bb = (const char*)Bw + bcol * 256;
  char* AsB = (char*)As;
  char* BsB = (char*)Bs;
  const int c0 = tid, c1 = tid + 256;
  const int r0 = c0 >> 2, o0 = (c0 & 3) * 16;
  const int r1 = c1 >> 2, o1 = (c1 & 3) * 16;

  for (int kk = 0; kk < 4; ++kk) {
    __syncthreads();
    const int kb = kk * 64;                        // 32 bf16 = 64 bytes of K
    gll16(Ab + (long)r0 * 256 + kb + o0, AsB + c0 * 16);
    gll16(Ab + (long)r1 * 256 + kb + o1, AsB + c1 * 16);
    gll16(Bb + (long)r0 * 256 + kb + o0, BsB + c0 * 16);
    gll16(Bb + (long)r1 * 256 + kb + o1, BsB + c1 * 16);
    __syncthreads();
    bf16x8 af[4], bfr[4];
#pragma unroll
    for (int mi = 0; mi < 4; ++mi)
      af[mi] = *(const bf16x8*)(As + (wr * 64 + mi * 16 + lr) * 32 + g * 8);
#pragma unroll
    for (int ni = 0; ni < 4; ++ni)
      bfr[ni] = *(const bf16x8*)(Bs + (wc * 64 + ni * 16 + lr) * 32 + g * 8);
#pragma unroll
    for (int mi = 0; mi < 4; ++mi)
#pragma unroll
      for (int ni = 0; ni < 4; ++ni)
        acc[mi][ni] = __builtin_amdgcn_mfma_f32_16x16x32_bf16(af[mi], bfr[ni], acc[mi][ni], 0, 0, 0);
  }

  if (PASS == 0) {
#pragma unroll
    for (int mi = 0; mi < 4; ++mi) {
#pragma unroll
      for (int r = 0; r < 4; ++r) {
        long row = brow + wr * 64 + mi * 16 + g * 4 + r;
        const float* urow = Ut + (long)(row / S_) * NPAD + bcol;
        float s = 0.f;
#pragma unroll
        for (int ni = 0; ni < 4; ++ni) {
          float u = urow[wc * 64 + ni * 16 + lr];
          s += __expf(acc[mi][ni][r] + u);
        }
#pragma unroll
        for (int off = 1; off < 16; off <<= 1) s += __shfl_xor(s, off);
        if (lr == 0) rsum2[wc][wr * 64 + mi * 16 + g * 4 + r] = s;
      }
    }
    __syncthreads();
    if (tid < 128)
      part[(long)bn * M_ + brow + tid] = rsum2[0][tid] + rsum2[1][tid];
  } else {
#pragma unroll
    for (int mi = 0; mi < 4; ++mi) {
#pragma unroll
      for (int r = 0; r < 4; ++r) {
        long row = brow + wr * 64 + mi * 16 + g * 4 + r;
        const float* urow = Ut + (long)(row / S_) * NPAD + bcol;
        float inv = 1.0f / rowsum[row];
        long base = row * (long)V_;
#pragma unroll
        for (int ni = 0; ni < 4; ++ni) {
          int col = (int)bcol + wc * 64 + ni * 16 + lr;
          float u = urow[wc * 64 + ni * 16 + lr];
          if (col < V_) y[base + col] = __expf(acc[mi][ni][r] + u) * inv;
        }
      }
    }
  }
}

__global__ void reduce_rows(const float* __restrict__ part, float* __restrict__ rowsum) {
  int m = blockIdx.x * 256 + threadIdx.x;            // grid 50 x 256
  if (m < M_) {
    float s = 0.f;
    for (int bn = 0; bn < NBN; ++bn) s += part[(long)bn * M_ + m];
    rowsum[m] = fmaxf(s, 1e-30f);
  }
}

// ---------------- launcher ----------------
extern "C" void kernel_launch(void* const* d_in, const int* in_sizes, int n_in,
                              void* d_out, int out_size, void* d_ws, size_t ws_size,
                              hipStream_t stream) {
  const int*   poi   = (const int*)d_in[0];
  // d_in[1] = lengths (all == S, unused)
  const float* ts    = (const float*)d_in[2];
  const float* loc   = (const float*)d_in[3];
  const int*   auser = (const int*)d_in[4];
  const float* embW  = (const float*)d_in[5];
  const float* userW = (const float*)d_in[6];
  const float* w_ih  = (const float*)d_in[7];
  const float* w_hh  = (const float*)d_in[8];
  const float* b_ih  = (const float*)d_in[9];
  const float* b_hh  = (const float*)d_in[10];
  const float* fcW   = (const float*)d_in[11];
  const float* fcb   = (const float*)d_in[12];

  float* out = (float*)d_out;
  char*  ws  = (char*)d_ws;
  __hip_bfloat16* Abf    = (__hip_bfloat16*)(ws + WS_A);
  __hip_bfloat16* w1b    = (__hip_bfloat16*)(ws + WS_FCW);
  float*          Ut     = (float*)(ws + WS_U);
  float*          rowsum = (float*)(ws + WS_RSUM);
  float*          wt_ih  = (float*)(ws + WS_WTIH);

  float* xp    = out + XP_OFF;     // scratch inside y region (overwritten by pass 1)
  float* hout  = out + HOUT_OFF;
  float* part  = out + PART_OFF;
  float* outpu = out + OUTPU_OFF;  // real output 1

  prep_w1<<<dim3(NPAD / 2), dim3(256), 0, stream>>>(fcW, w1b);
  prep_wt<<<dim3(128), dim3(128), 0, stream>>>(w_ih, wt_ih);
  user_k<<<dim3(NPAD / 256, 8), dim3(256), 0, stream>>>(auser, userW, fcW, fcb, Ut);
  xproj_k<<<dim3(M_), dim3(128), 0, stream>>>(poi, embW, wt_ih, b_ih, b_hh, xp);
  rnn_k<<<dim3(B_), dim3(128), 0, stream>>>(xp, w_hh, hout);
  attn_k<<<dim3(S_, B_), dim3(128), 0, stream>>>(ts, loc, hout, auser, userW, outpu, Abf);
  gemm_fc<0><<<dim3(NWG2), dim3(256), 0, stream>>>(Abf, w1b, Ut, nullptr, part, nullptr);
  reduce_rows<<<dim3(50), dim3(256), 0, stream>>>(part, rowsum);
  gemm_fc<1><<<dim3(NWG2), dim3(256), 0, stream>>>(Abf, w1b, Ut, rowsum, nullptr, out);
}

// Round 5
// 828.198 us; speedup vs baseline: 1.2928x; 1.0724x over previous
//
#include <hip/hip_runtime.h>
#include <hip/hip_bf16.h>
#include <stdint.h>

// Problem constants
#define B_   64
#define S_   200
#define H_   128
#define V_   20000
#define M_   12800      // B_*S_
#define NPAD 20224      // 158*128
#define NBN  158        // N blocks of 128
#define NBM  100        // M blocks of 128
#define NWG2 15800      // NBN*NBM (== 8*1975)

// ws offsets (bytes) — total ~13.7 MB
#define WS_A      0u          // A1_bf16 [12800][128]      3,276,800 B
#define WS_FCW    3276800u    // W1_bf16 [20224][128]      5,177,344 B
#define WS_U      8454144u    // U [64][20224] f32         5,177,344 B
#define WS_RSUM   13631488u   // rowsum [12800] f32           51,200 B
#define WS_WTIH   13682688u   // W_ih^T [128][128] f32        65,536 B
// end 13,748,224

// scratch inside the y region of d_out (float offsets) — overwritten by final pass
#define XP_OFF    0
#define HOUT_OFF  2000000
#define PART_OFF  4000000          // [NBN][12800] partial exp-sums (2.02M floats)
#define OUTPU_OFF 256000000ll      // real output 1 (out_pu)

typedef __attribute__((ext_vector_type(8))) __bf16 bf16x8;
typedef __attribute__((ext_vector_type(4))) float  f32x4;

__device__ __forceinline__ void gll16(const void* g, void* l) {
  __builtin_amdgcn_global_load_lds(
      (const __attribute__((address_space(1))) void*)g,
      (__attribute__((address_space(3))) void*)l, 16, 0, 0);
}

// ---------------- prep: W1 bf16 (first 128 cols of fc_W) ----------------
__global__ __launch_bounds__(256)
void prep_w1(const float* __restrict__ fcw, __hip_bfloat16* __restrict__ w1) {
  int t = threadIdx.x;
  int row = blockIdx.x * 2 + (t >> 7);          // grid 10112 x 256
  int col = t & 127;
  float v = (row < V_) ? fcw[(long)row * 256 + col] : 0.f;
  w1[(long)row * 128 + col] = __float2bfloat16(v);
}

// ---------------- prep: W_ih transpose ----------------
__global__ __launch_bounds__(128)
void prep_wt(const float* __restrict__ w_ih, float* __restrict__ wt) {
  int bid = blockIdx.x, t = threadIdx.x;        // grid 128 x 128
  wt[bid * 128 + t] = w_ih[t * 128 + bid];      // wt[k][j] = W_ih[j][k]
}

// ---------------- U table: U[b][c] = p_u(b) . fcW[c,128:256] + fcb[c] ----------------
__global__ __launch_bounds__(256)
void user_k(const int* __restrict__ auser, const float* __restrict__ userW,
            const float* __restrict__ fcW, const float* __restrict__ fcb,
            float* __restrict__ U) {
  __shared__ float uw[8][128];
  int t = threadIdx.x;
  int c = blockIdx.x * 256 + t;                 // grid (79, 8)
  int b0 = blockIdx.y * 8;
  for (int i = t; i < 8 * 128; i += 256) {
    int bb = i >> 7, kk = i & 127;
    uw[bb][kk] = userW[(long)auser[b0 + bb] * 128 + kk];
  }
  __syncthreads();
  float acc[8];
#pragma unroll
  for (int bb = 0; bb < 8; ++bb) acc[bb] = 0.f;
  if (c < V_) {
    const float* w2 = fcW + (long)c * 256 + 128;
#pragma unroll 4
    for (int k = 0; k < 128; k += 4) {
      float4 wv = *(const float4*)(w2 + k);
#pragma unroll
      for (int bb = 0; bb < 8; ++bb) {
        acc[bb] = fmaf(wv.x, uw[bb][k], acc[bb]);
        acc[bb] = fmaf(wv.y, uw[bb][k + 1], acc[bb]);
        acc[bb] = fmaf(wv.z, uw[bb][k + 2], acc[bb]);
        acc[bb] = fmaf(wv.w, uw[bb][k + 3], acc[bb]);
      }
    }
    float base = fcb[c];
#pragma unroll
    for (int bb = 0; bb < 8; ++bb)
      U[(long)(b0 + bb) * NPAD + c] = base + acc[bb];
  } else {
#pragma unroll
    for (int bb = 0; bb < 8; ++bb)
      U[(long)(b0 + bb) * NPAD + c] = -1e30f;    // pad cols: exp -> 0
  }
}

// ---------------- K1: x_proj = emb[poi] @ W_ih^T + b_ih + b_hh ----------------
__global__ __launch_bounds__(128)
void xproj_k(const int* __restrict__ poi, const float* __restrict__ emb,
             const float* __restrict__ wt_ih, const float* __restrict__ b_ih,
             const float* __restrict__ b_hh, float* __restrict__ xp) {
  __shared__ float xs[128];
  int m = blockIdx.x, j = threadIdx.x;               // grid 12800 x 128
  xs[j] = emb[(long)poi[m] * 128 + j];
  __syncthreads();
  float acc = b_ih[j] + b_hh[j];
#pragma unroll 8
  for (int k = 0; k < 128; ++k) acc = fmaf(xs[k], wt_ih[k * 128 + j], acc);
  xp[(long)m * 128 + j] = acc;
}

// ---------------- K2: sequential RNN (4-way split dep chain) ----------------
__global__ __launch_bounds__(128)
void rnn_k(const float* __restrict__ xp, const float* __restrict__ w_hh,
           float* __restrict__ hout) {
  int b = blockIdx.x, j = threadIdx.x;               // grid 64 x 128
  float w[128];
#pragma unroll
  for (int k = 0; k < 128; ++k) w[k] = w_hh[j * 128 + k];
  __shared__ float hs[2][128];
  hs[0][j] = 0.f;
  __syncthreads();
  int cur = 0;
  for (int t = 0; t < S_; ++t) {
    float x0 = xp[((long)b * S_ + t) * 128 + j];
    const float* hp = hs[cur];
    float a0 = 0.f, a1 = 0.f, a2 = 0.f, a3 = 0.f;
#pragma unroll
    for (int k = 0; k < 32; ++k) {
      a0 = fmaf(hp[k],      w[k],      a0);
      a1 = fmaf(hp[k + 32], w[k + 32], a1);
      a2 = fmaf(hp[k + 64], w[k + 64], a2);
      a3 = fmaf(hp[k + 96], w[k + 96], a3);
    }
    float hn = tanhf(x0 + ((a0 + a1) + (a2 + a3)));
    hs[cur ^ 1][j] = hn;
    hout[((long)b * S_ + t) * 128 + j] = hn;
    cur ^= 1;
    __syncthreads();
  }
}

// ---------------- K3: decay attention + out_pu + A1 bf16 ----------------
__global__ __launch_bounds__(128)
void attn_k(const float* __restrict__ ts, const float* __restrict__ loc,
            const float* __restrict__ hout, const int* __restrict__ auser,
            const float* __restrict__ userW, float* __restrict__ outpu,
            __hip_bfloat16* __restrict__ Abf) {
  int i = blockIdx.x, b = blockIdx.y, h = threadIdx.x;   // grid (200,64) x 128
  __shared__ float wl[128];
  const float OMEGA = 7.27220521664304e-05f;             // 2*pi/86400
  float ti = ts[b * S_ + i];
  float lx = loc[(b * S_ + i) * 2 + 0];
  float ly = loc[(b * S_ + i) * 2 + 1];
  float acc = 0.f, sw = 0.f;
  for (int jc = 0; jc <= i; jc += 128) {
    int j = jc + h;
    float wj = 0.f;
    if (j <= i) {
      float dt = fmaxf(ti - ts[b * S_ + j], 0.f);
      float a = (cosf(dt * OMEGA) + 1.f) * 0.5f * expf(-dt * 0.01f);
      float dx = lx - loc[(b * S_ + j) * 2 + 0];
      float dy = ly - loc[(b * S_ + j) * 2 + 1];
      float dn = sqrtf(dx * dx + dy * dy);
      wj = a * expf(-dn * 100.f) + 1e-10f;
    }
    __syncthreads();
    wl[h] = wj;
    __syncthreads();
    int lim = min(128, i - jc + 1);
    const float* hb = hout + ((long)b * S_ + jc) * 128 + h;
    for (int jj = 0; jj < lim; ++jj) {
      float wv = wl[jj];
      acc = fmaf(wv, hb[(long)jj * 128], acc);
      sw += wv;
    }
  }
  float ow = acc / fmaxf(sw, 1e-10f);
  long m = (long)b * S_ + i;
  float pu = userW[(long)auser[b] * 128 + h];
  outpu[m * 256 + h]       = ow;
  outpu[m * 256 + 128 + h] = pu;
  Abf[m * 128 + h]         = __float2bfloat16(ow);   // only out_w half feeds GEMM
}

// ---------------- K4/K5: FC GEMM, K=128, 128x128 tile (m97/r1 structure) ----------------
// logit(r,c) = acc(r,c) + U[r/200][c];  PASS0: rowsum partials;  PASS1: y = exp/rowsum
// PASS1 epilogue: stage tile in LDS (reusing As/Bs), write y fully coalesced (float4).
template <int PASS>
__global__ __launch_bounds__(256)
void gemm_fc(const __hip_bfloat16* __restrict__ A,    // [12800][128]
             const __hip_bfloat16* __restrict__ Bw,   // [20224][128]
             const float* __restrict__ Ut,            // [64][20224]
             const float* __restrict__ rowsum,        // [12800] (PASS 1)
             float* __restrict__ part,                 // [NBN][12800] (PASS 0)
             float* __restrict__ y) {                  // [12800][20000] (PASS 1)
  __shared__ __align__(16) char smem[32768];     // As(8K)+Bs(8K) main loop; lbuf 32K epilogue
  __shared__ float rsum2[2][128];
  char* AsB = smem;
  char* BsB = smem + 8192;
  float* lbuf = (float*)smem;                    // [64][128] f32 (PASS 1 epilogue)

  const int tid  = threadIdx.x;
  const int lane = tid & 63;
  const int wid  = tid >> 6;
  const int wr = wid >> 1, wc = wid & 1;
  const int g = lane >> 4, lr = lane & 15;

  // bijective XCD swizzle: 15800 = 8*1975; each XCD gets ~20 contiguous N-panels
  const int orig = blockIdx.x;
  const int nid = (orig & 7) * (NWG2 / 8) + (orig >> 3);
  const int bn = nid / NBM, bm = nid % NBM;
  const long brow = (long)bm * 128, bcol = (long)bn * 128;

  f32x4 acc[4][4];
#pragma unroll
  for (int mi = 0; mi < 4; ++mi)
#pragma unroll
    for (int ni = 0; ni < 4; ++ni) acc[mi][ni] = (f32x4)(0.f);

  const char* Ab = (const char*)A + brow * 256;   // row stride 128*2B
  const char* Bb = (const char*)Bw + bcol * 256;
  const int c0 = tid, c1 = tid + 256;
  const int r0 = c0 >> 2, o0 = (c0 & 3) * 16;
  const int r1 = c1 >> 2, o1 = (c1 & 3) * 16;

  for (int kk = 0; kk < 4; ++kk) {
    __syncthreads();
    const int kb = kk * 64;                        // 32 bf16 = 64 bytes of K
    gll16(Ab + (long)r0 * 256 + kb + o0, AsB + c0 * 16);
    gll16(Ab + (long)r1 * 256 + kb + o1, AsB + c1 * 16);
    gll16(Bb + (long)r0 * 256 + kb + o0, BsB + c0 * 16);
    gll16(Bb + (long)r1 * 256 + kb + o1, BsB + c1 * 16);
    __syncthreads();
    bf16x8 af[4], bfr[4];
#pragma unroll
    for (int mi = 0; mi < 4; ++mi)
      af[mi] = *(const bf16x8*)(AsB + (wr * 64 + mi * 16 + lr) * 64 + g * 16);
#pragma unroll
    for (int ni = 0; ni < 4; ++ni)
      bfr[ni] = *(const bf16x8*)(BsB + (wc * 64 + ni * 16 + lr) * 64 + g * 16);
#pragma unroll
    for (int mi = 0; mi < 4; ++mi)
#pragma unroll
      for (int ni = 0; ni < 4; ++ni)
        acc[mi][ni] = __builtin_amdgcn_mfma_f32_16x16x32_bf16(af[mi], bfr[ni], acc[mi][ni], 0, 0, 0);
  }

  if (PASS == 0) {
#pragma unroll
    for (int mi = 0; mi < 4; ++mi) {
#pragma unroll
      for (int r = 0; r < 4; ++r) {
        long row = brow + wr * 64 + mi * 16 + g * 4 + r;
        const float* urow = Ut + (long)(row / S_) * NPAD + bcol;
        float s = 0.f;
#pragma unroll
        for (int ni = 0; ni < 4; ++ni) {
          float u = urow[wc * 64 + ni * 16 + lr];
          s += __expf(acc[mi][ni][r] + u);
        }
#pragma unroll
        for (int off = 1; off < 16; off <<= 1) s += __shfl_xor(s, off);
        if (lr == 0) rsum2[wc][wr * 64 + mi * 16 + g * 4 + r] = s;
      }
    }
    __syncthreads();
    if (tid < 128)
      part[(long)bn * M_ + brow + tid] = rsum2[0][tid] + rsum2[1][tid];
  } else {
    if (bcol >= V_) return;                      // fully-OOB N panel (bn==157)
    const bool full = (bcol + 128 <= V_);
    // two half-tiles of 64 rows through 32 KB LDS, coalesced float4 stores
#pragma unroll
    for (int half = 0; half < 2; ++half) {
      __syncthreads();                            // As/Bs (or prev lbuf) dead
      if (wr == half) {
#pragma unroll
        for (int mi = 0; mi < 4; ++mi) {
#pragma unroll
          for (int r = 0; r < 4; ++r) {
            int lrow = mi * 16 + g * 4 + r;       // 0..63
            long row = brow + half * 64 + lrow;
            const float* urow = Ut + (long)(row / S_) * NPAD + bcol;
            float inv = 1.0f / rowsum[row];
#pragma unroll
            for (int ni = 0; ni < 4; ++ni) {
              int lcol = wc * 64 + ni * 16 + lr;
              lbuf[lrow * 128 + lcol] = __expf(acc[mi][ni][r] + urow[lcol]) * inv;
            }
          }
        }
      }
      __syncthreads();
      if (full) {
#pragma unroll
        for (int it = 0; it < 8; ++it) {
          int idx = it * 256 + tid;               // 0..2047 float4 slots
          int lrow = idx >> 5, c4 = idx & 31;
          long row = brow + half * 64 + lrow;
          *(float4*)(y + row * (long)V_ + bcol + c4 * 4) = ((const float4*)lbuf)[idx];
        }
      } else {
#pragma unroll
        for (int it = 0; it < 8; ++it) {
          int idx = it * 256 + tid;
          int lrow = idx >> 5, c4 = idx & 31;
          long row = brow + half * 64 + lrow;
#pragma unroll
          for (int e = 0; e < 4; ++e) {
            int col = (int)bcol + c4 * 4 + e;
            if (col < V_) y[row * (long)V_ + col] = lbuf[lrow * 128 + c4 * 4 + e];
          }
        }
      }
    }
  }
}

__global__ void reduce_rows(const float* __restrict__ part, float* __restrict__ rowsum) {
  int m = blockIdx.x * 256 + threadIdx.x;            // grid 50 x 256
  if (m < M_) {
    float s = 0.f;
    for (int bn = 0; bn < NBN; ++bn) s += part[(long)bn * M_ + m];
    rowsum[m] = fmaxf(s, 1e-30f);
  }
}

// ---------------- launcher ----------------
extern "C" void kernel_launch(void* const* d_in, const int* in_sizes, int n_in,
                              void* d_out, int out_size, void* d_ws, size_t ws_size,
                              hipStream_t stream) {
  const int*   poi   = (const int*)d_in[0];
  // d_in[1] = lengths (all == S, unused)
  const float* ts    = (const float*)d_in[2];
  const float* loc   = (const float*)d_in[3];
  const int*   auser = (const int*)d_in[4];
  const float* embW  = (const float*)d_in[5];
  const float* userW = (const float*)d_in[6];
  const float* w_ih  = (const float*)d_in[7];
  const float* w_hh  = (const float*)d_in[8];
  const float* b_ih  = (const float*)d_in[9];
  const float* b_hh  = (const float*)d_in[10];
  const float* fcW   = (const float*)d_in[11];
  const float* fcb   = (const float*)d_in[12];

  float* out = (float*)d_out;
  char*  ws  = (char*)d_ws;
  __hip_bfloat16* Abf    = (__hip_bfloat16*)(ws + WS_A);
  __hip_bfloat16* w1b    = (__hip_bfloat16*)(ws + WS_FCW);
  float*          Ut     = (float*)(ws + WS_U);
  float*          rowsum = (float*)(ws + WS_RSUM);
  float*          wt_ih  = (float*)(ws + WS_WTIH);

  float* xp    = out + XP_OFF;     // scratch inside y region (overwritten by pass 1)
  float* hout  = out + HOUT_OFF;
  float* part  = out + PART_OFF;
  float* outpu = out + OUTPU_OFF;  // real output 1

  prep_w1<<<dim3(NPAD / 2), dim3(256), 0, stream>>>(fcW, w1b);
  prep_wt<<<dim3(128), dim3(128), 0, stream>>>(w_ih, wt_ih);
  user_k<<<dim3(NPAD / 256, 8), dim3(256), 0, stream>>>(auser, userW, fcW, fcb, Ut);
  xproj_k<<<dim3(M_), dim3(128), 0, stream>>>(poi, embW, wt_ih, b_ih, b_hh, xp);
  rnn_k<<<dim3(B_), dim3(128), 0, stream>>>(xp, w_hh, hout);
  attn_k<<<dim3(S_, B_), dim3(128), 0, stream>>>(ts, loc, hout, auser, userW, outpu, Abf);
  gemm_fc<0><<<dim3(NWG2), dim3(256), 0, stream>>>(Abf, w1b, Ut, nullptr, part, nullptr);
  reduce_rows<<<dim3(50), dim3(256), 0, stream>>>(part, rowsum);
  gemm_fc<1><<<dim3(NWG2), dim3(256), 0, stream>>>(Abf, w1b, Ut, rowsum, nullptr, out);
}

// Round 6
// 807.306 us; speedup vs baseline: 1.3263x; 1.0259x over previous
//
#include <hip/hip_runtime.h>
#include <hip/hip_bf16.h>
#include <stdint.h>

// Problem constants
#define B_   64
#define S_   200
#define H_   128
#define V_   20000
#define M_   12800      // B_*S_
#define NPAD 20224      // 79*256
#define NBN  79         // N blocks of 256
#define NBM  50         // M blocks of 256
#define NWG  3950       // NBN*NBM

// ws offsets (bytes) — total ~13.7 MB
#define WS_A      0u          // A1_bf16 [12800][128]      3,276,800 B
#define WS_FCW    3276800u    // W1_bf16 [20224][128]      5,177,344 B
#define WS_U      8454144u    // U [64][20224] f32         5,177,344 B
#define WS_RSUM   13631488u   // rowsum [12800] f32           51,200 B
#define WS_WTIH   13682688u   // W_ih^T [128][128] f32        65,536 B
// end 13,748,224

// scratch inside the y region of d_out (float offsets) — overwritten by final pass
#define XP_OFF    0
#define HOUT_OFF  2000000
#define PART_OFF  4000000          // [NBN][12800] partial exp-sums (1.01M floats)
#define OUTPU_OFF 256000000ll      // real output 1 (out_pu)

typedef __attribute__((ext_vector_type(8))) __bf16 bf16x8;
typedef __attribute__((ext_vector_type(4))) float  f32x4;

__device__ __forceinline__ void gll16(const void* g, void* l) {
  __builtin_amdgcn_global_load_lds(
      (const __attribute__((address_space(1))) void*)g,
      (__attribute__((address_space(3))) void*)l, 16, 0, 0);
}

// ---------------- prep: W1 bf16 (first 128 cols of fc_W) ----------------
__global__ __launch_bounds__(256)
void prep_w1(const float* __restrict__ fcw, __hip_bfloat16* __restrict__ w1) {
  int t = threadIdx.x;
  int row = blockIdx.x * 2 + (t >> 7);          // grid 10112 x 256
  int col = t & 127;
  float v = (row < V_) ? fcw[(long)row * 256 + col] : 0.f;
  w1[(long)row * 128 + col] = __float2bfloat16(v);
}

// ---------------- prep: W_ih transpose ----------------
__global__ __launch_bounds__(128)
void prep_wt(const float* __restrict__ w_ih, float* __restrict__ wt) {
  int bid = blockIdx.x, t = threadIdx.x;        // grid 128 x 128
  wt[bid * 128 + t] = w_ih[t * 128 + bid];      // wt[k][j] = W_ih[j][k]
}

// ---------------- U table: U[b][c] = p_u(b) . fcW[c,128:256] + fcb[c] ----------------
__global__ __launch_bounds__(256)
void user_k(const int* __restrict__ auser, const float* __restrict__ userW,
            const float* __restrict__ fcW, const float* __restrict__ fcb,
            float* __restrict__ U) {
  __shared__ float uw[8][128];
  int t = threadIdx.x;
  int c = blockIdx.x * 256 + t;                 // grid (79, 8)
  int b0 = blockIdx.y * 8;
  for (int i = t; i < 8 * 128; i += 256) {
    int bb = i >> 7, kk = i & 127;
    uw[bb][kk] = userW[(long)auser[b0 + bb] * 128 + kk];
  }
  __syncthreads();
  float acc[8];
#pragma unroll
  for (int bb = 0; bb < 8; ++bb) acc[bb] = 0.f;
  if (c < V_) {
    const float* w2 = fcW + (long)c * 256 + 128;
#pragma unroll 4
    for (int k = 0; k < 128; k += 4) {
      float4 wv = *(const float4*)(w2 + k);
#pragma unroll
      for (int bb = 0; bb < 8; ++bb) {
        acc[bb] = fmaf(wv.x, uw[bb][k], acc[bb]);
        acc[bb] = fmaf(wv.y, uw[bb][k + 1], acc[bb]);
        acc[bb] = fmaf(wv.z, uw[bb][k + 2], acc[bb]);
        acc[bb] = fmaf(wv.w, uw[bb][k + 3], acc[bb]);
      }
    }
    float base = fcb[c];
#pragma unroll
    for (int bb = 0; bb < 8; ++bb)
      U[(long)(b0 + bb) * NPAD + c] = base + acc[bb];
  } else {
#pragma unroll
    for (int bb = 0; bb < 8; ++bb)
      U[(long)(b0 + bb) * NPAD + c] = -1e30f;    // pad cols: exp -> 0
  }
}

// ---------------- K1: x_proj = emb[poi] @ W_ih^T + b_ih + b_hh ----------------
__global__ __launch_bounds__(128)
void xproj_k(const int* __restrict__ poi, const float* __restrict__ emb,
             const float* __restrict__ wt_ih, const float* __restrict__ b_ih,
             const float* __restrict__ b_hh, float* __restrict__ xp) {
  __shared__ float xs[128];
  int m = blockIdx.x, j = threadIdx.x;               // grid 12800 x 128
  xs[j] = emb[(long)poi[m] * 128 + j];
  __syncthreads();
  float acc = b_ih[j] + b_hh[j];
#pragma unroll 8
  for (int k = 0; k < 128; ++k) acc = fmaf(xs[k], wt_ih[k * 128 + j], acc);
  xp[(long)m * 128 + j] = acc;
}

// ---------------- K2: sequential RNN (4-way split dep chain) ----------------
__global__ __launch_bounds__(128)
void rnn_k(const float* __restrict__ xp, const float* __restrict__ w_hh,
           float* __restrict__ hout) {
  int b = blockIdx.x, j = threadIdx.x;               // grid 64 x 128
  float w[128];
#pragma unroll
  for (int k = 0; k < 128; ++k) w[k] = w_hh[j * 128 + k];
  __shared__ float hs[2][128];
  hs[0][j] = 0.f;
  __syncthreads();
  int cur = 0;
  for (int t = 0; t < S_; ++t) {
    float x0 = xp[((long)b * S_ + t) * 128 + j];
    const float* hp = hs[cur];
    float a0 = 0.f, a1 = 0.f, a2 = 0.f, a3 = 0.f;
#pragma unroll
    for (int k = 0; k < 32; ++k) {
      a0 = fmaf(hp[k],      w[k],      a0);
      a1 = fmaf(hp[k + 32], w[k + 32], a1);
      a2 = fmaf(hp[k + 64], w[k + 64], a2);
      a3 = fmaf(hp[k + 96], w[k + 96], a3);
    }
    float hn = tanhf(x0 + ((a0 + a1) + (a2 + a3)));
    hs[cur ^ 1][j] = hn;
    hout[((long)b * S_ + t) * 128 + j] = hn;
    cur ^= 1;
    __syncthreads();
  }
}

// ---------------- K3: decay attention + out_pu + A1 bf16 ----------------
__global__ __launch_bounds__(128)
void attn_k(const float* __restrict__ ts, const float* __restrict__ loc,
            const float* __restrict__ hout, const int* __restrict__ auser,
            const float* __restrict__ userW, float* __restrict__ outpu,
            __hip_bfloat16* __restrict__ Abf) {
  int i = blockIdx.x, b = blockIdx.y, h = threadIdx.x;   // grid (200,64) x 128
  __shared__ float wl[128];
  const float OMEGA = 7.27220521664304e-05f;             // 2*pi/86400
  float ti = ts[b * S_ + i];
  float lx = loc[(b * S_ + i) * 2 + 0];
  float ly = loc[(b * S_ + i) * 2 + 1];
  float acc = 0.f, sw = 0.f;
  for (int jc = 0; jc <= i; jc += 128) {
    int j = jc + h;
    float wj = 0.f;
    if (j <= i) {
      float dt = fmaxf(ti - ts[b * S_ + j], 0.f);
      float a = (cosf(dt * OMEGA) + 1.f) * 0.5f * expf(-dt * 0.01f);
      float dx = lx - loc[(b * S_ + j) * 2 + 0];
      float dy = ly - loc[(b * S_ + j) * 2 + 1];
      float dn = sqrtf(dx * dx + dy * dy);
      wj = a * expf(-dn * 100.f) + 1e-10f;
    }
    __syncthreads();
    wl[h] = wj;
    __syncthreads();
    int lim = min(128, i - jc + 1);
    const float* hb = hout + ((long)b * S_ + jc) * 128 + h;
    for (int jj = 0; jj < lim; ++jj) {
      float wv = wl[jj];
      acc = fmaf(wv, hb[(long)jj * 128], acc);
      sw += wv;
    }
  }
  float ow = acc / fmaxf(sw, 1e-10f);
  long m = (long)b * S_ + i;
  float pu = userW[(long)auser[b] * 128 + h];
  outpu[m * 256 + h]       = ow;
  outpu[m * 256 + 128 + h] = pu;
  Abf[m * 128 + h]         = __float2bfloat16(ow);   // only out_w half feeds GEMM
}

// ---------------- K4/K5: FC GEMM, K=128 ONE-SHOT, 256x256 tile ----------------
// Whole K staged once into LDS (128 KB, XOR-swizzled via pre-swizzled global src),
// one barrier pair, 128 MFMA/wave uninterrupted.
// logit(r,c) = acc(r,c) + U[r/200][c];  PASS0: rowsum partials;  PASS1: y = exp/rowsum
template <int PASS>
__global__ __launch_bounds__(512)
void gemm_fc(const __hip_bfloat16* __restrict__ A,    // [12800][128]
             const __hip_bfloat16* __restrict__ Bw,   // [20224][128]
             const float* __restrict__ Ut,            // [64][20224]
             const float* __restrict__ rowsum,        // [12800] (PASS 1)
             float* __restrict__ part,                 // [NBN][12800] (PASS 0)
             float* __restrict__ y) {                  // [12800][20000] (PASS 1)
  __shared__ __align__(16) char smem[131072];    // As 64K | Bs 64K ; lbuf reuses all
  __shared__ float rsum4[4][256];
  char* AsB = smem;
  char* BsB = smem + 65536;
  float* lbuf = (float*)smem;                    // [128][256] f32 (PASS 1 epilogue)

  const int tid  = threadIdx.x;
  const int lane = tid & 63;
  const int wid  = tid >> 6;               // 0..7
  const int wr = wid >> 2, wc = wid & 3;   // 2(M) x 4(N); wave tile 128x64
  const int g = lane >> 4, lr = lane & 15;

  // bijective XCD swizzle (m204): 3950 = 8 XCDs, q=493 r=6
  const int orig = blockIdx.x;
  const int qq = NWG >> 3, rr = NWG & 7;
  const int xcd = orig & 7, lix = orig >> 3;
  const int nid = (xcd < rr ? xcd * (qq + 1) : rr * (qq + 1) + (xcd - rr) * qq) + lix;
  const int bn = nid / NBM, bm = nid % NBM;
  const long brow = (long)bm * 256, bcol = (long)bn * 256;

  const char* Ab = (const char*)A + brow * 256;   // row stride 128*2B
  const char* Bb = (const char*)Bw + bcol * 256;

  // one-shot stage: 64 KB A + 64 KB B. LDS dest linear; global src pre-swizzled
  // (w ^= row&7 on 16B units) so swizzled ds_reads see conflict-free layout.
#pragma unroll
  for (int i = 0; i < 8; ++i) {
    int ci = i * 512 + tid;                  // 0..4095 16B-chunks
    int row = ci >> 4;                        // 0..255
    int w = (ci & 15) ^ (row & 7);
    long src = (long)row * 256 + (long)w * 16;
    gll16(Ab + src, AsB + (long)ci * 16);
    gll16(Bb + src, BsB + (long)ci * 16);
  }
  __syncthreads();                            // waits vmcnt(0): tiles resident

  f32x4 acc[8][4];
#pragma unroll
  for (int mi = 0; mi < 8; ++mi)
#pragma unroll
    for (int ni = 0; ni < 4; ++ni) acc[mi][ni] = (f32x4)(0.f);

#pragma unroll
  for (int kk = 0; kk < 4; ++kk) {
    bf16x8 af[8], bfr[4];
#pragma unroll
    for (int mi = 0; mi < 8; ++mi) {
      int row = wr * 128 + mi * 16 + lr;
      int w = ((kk << 2) | g) ^ (row & 7);
      af[mi] = *(const bf16x8*)(AsB + row * 256 + w * 16);
    }
#pragma unroll
    for (int ni = 0; ni < 4; ++ni) {
      int row = wc * 64 + ni * 16 + lr;
      int w = ((kk << 2) | g) ^ (row & 7);
      bfr[ni] = *(const bf16x8*)(BsB + row * 256 + w * 16);
    }
#pragma unroll
    for (int mi = 0; mi < 8; ++mi)
#pragma unroll
      for (int ni = 0; ni < 4; ++ni)
        acc[mi][ni] = __builtin_amdgcn_mfma_f32_16x16x32_bf16(af[mi], bfr[ni], acc[mi][ni], 0, 0, 0);
  }

  if (PASS == 0) {
#pragma unroll
    for (int mi = 0; mi < 8; ++mi) {
#pragma unroll
      for (int r = 0; r < 4; ++r) {
        long row = brow + wr * 128 + mi * 16 + g * 4 + r;
        const float* urow = Ut + (long)(row / S_) * NPAD + bcol;
        float s = 0.f;
#pragma unroll
        for (int ni = 0; ni < 4; ++ni) {
          float u = urow[wc * 64 + ni * 16 + lr];
          s += __expf(acc[mi][ni][r] + u);
        }
#pragma unroll
        for (int off = 1; off < 16; off <<= 1) s += __shfl_xor(s, off);
        if (lr == 0) rsum4[wc][wr * 128 + mi * 16 + g * 4 + r] = s;
      }
    }
    __syncthreads();
    if (tid < 256)
      part[(long)bn * M_ + brow + tid] =
          rsum4[0][tid] + rsum4[1][tid] + rsum4[2][tid] + rsum4[3][tid];
  } else {
    const bool full = (bcol + 256 <= V_);     // bn<78 full; bn==78 has 32 valid cols
    // two halves of 128 rows through 128 KB LDS, coalesced float4 stores
#pragma unroll
    for (int half = 0; half < 2; ++half) {
      __syncthreads();                         // As/Bs (or prev lbuf) dead
      if (wr == half) {
#pragma unroll
        for (int mi = 0; mi < 8; ++mi) {
#pragma unroll
          for (int r = 0; r < 4; ++r) {
            int lrow = mi * 16 + g * 4 + r;    // 0..127
            long row = brow + half * 128 + lrow;
            const float* urow = Ut + (long)(row / S_) * NPAD + bcol;
            float inv = 1.0f / rowsum[row];
#pragma unroll
            for (int ni = 0; ni < 4; ++ni) {
              int lcol = wc * 64 + ni * 16 + lr;
              lbuf[lrow * 256 + lcol] = __expf(acc[mi][ni][r] + urow[lcol]) * inv;
            }
          }
        }
      }
      __syncthreads();
      if (full) {
#pragma unroll
        for (int it = 0; it < 16; ++it) {
          int idx = it * 512 + tid;            // 0..8191 float4 slots
          int lrow = idx >> 6, c4 = idx & 63;
          long row = brow + half * 128 + lrow;
          *(float4*)(y + row * (long)V_ + bcol + c4 * 4) = ((const float4*)lbuf)[idx];
        }
      } else {
#pragma unroll
        for (int it = 0; it < 16; ++it) {
          int idx = it * 512 + tid;
          int lrow = idx >> 6, c4 = idx & 63;
          long row = brow + half * 128 + lrow;
#pragma unroll
          for (int e = 0; e < 4; ++e) {
            int col = (int)bcol + c4 * 4 + e;
            if (col < V_) y[row * (long)V_ + col] = lbuf[lrow * 256 + c4 * 4 + e];
          }
        }
      }
    }
  }
}

__global__ void reduce_rows(const float* __restrict__ part, float* __restrict__ rowsum) {
  int m = blockIdx.x * 256 + threadIdx.x;            // grid 50 x 256
  if (m < M_) {
    float s = 0.f;
    for (int bn = 0; bn < NBN; ++bn) s += part[(long)bn * M_ + m];
    rowsum[m] = fmaxf(s, 1e-30f);
  }
}

// ---------------- launcher ----------------
extern "C" void kernel_launch(void* const* d_in, const int* in_sizes, int n_in,
                              void* d_out, int out_size, void* d_ws, size_t ws_size,
                              hipStream_t stream) {
  const int*   poi   = (const int*)d_in[0];
  // d_in[1] = lengths (all == S, unused)
  const float* ts    = (const float*)d_in[2];
  const float* loc   = (const float*)d_in[3];
  const int*   auser = (const int*)d_in[4];
  const float* embW  = (const float*)d_in[5];
  const float* userW = (const float*)d_in[6];
  const float* w_ih  = (const float*)d_in[7];
  const float* w_hh  = (const float*)d_in[8];
  const float* b_ih  = (const float*)d_in[9];
  const float* b_hh  = (const float*)d_in[10];
  const float* fcW   = (const float*)d_in[11];
  const float* fcb   = (const float*)d_in[12];

  float* out = (float*)d_out;
  char*  ws  = (char*)d_ws;
  __hip_bfloat16* Abf    = (__hip_bfloat16*)(ws + WS_A);
  __hip_bfloat16* w1b    = (__hip_bfloat16*)(ws + WS_FCW);
  float*          Ut     = (float*)(ws + WS_U);
  float*          rowsum = (float*)(ws + WS_RSUM);
  float*          wt_ih  = (float*)(ws + WS_WTIH);

  float* xp    = out + XP_OFF;     // scratch inside y region (overwritten by pass 1)
  float* hout  = out + HOUT_OFF;
  float* part  = out + PART_OFF;
  float* outpu = out + OUTPU_OFF;  // real output 1

  prep_w1<<<dim3(NPAD / 2), dim3(256), 0, stream>>>(fcW, w1b);
  prep_wt<<<dim3(128), dim3(128), 0, stream>>>(w_ih, wt_ih);
  user_k<<<dim3(NPAD / 256, 8), dim3(256), 0, stream>>>(auser, userW, fcW, fcb, Ut);
  xproj_k<<<dim3(M_), dim3(128), 0, stream>>>(poi, embW, wt_ih, b_ih, b_hh, xp);
  rnn_k<<<dim3(B_), dim3(128), 0, stream>>>(xp, w_hh, hout);
  attn_k<<<dim3(S_, B_), dim3(128), 0, stream>>>(ts, loc, hout, auser, userW, outpu, Abf);
  gemm_fc<0><<<dim3(NWG), dim3(512), 0, stream>>>(Abf, w1b, Ut, nullptr, part, nullptr);
  reduce_rows<<<dim3(50), dim3(256), 0, stream>>>(part, rowsum);
  gemm_fc<1><<<dim3(NWG), dim3(512), 0, stream>>>(Abf, w1b, Ut, rowsum, nullptr, out);
}

// Round 8
// 737.168 us; speedup vs baseline: 1.4525x; 1.0951x over previous
//
#include <hip/hip_runtime.h>
#include <hip/hip_bf16.h>
#include <stdint.h>

// Problem constants
#define B_   64
#define S_   200
#define H_   128
#define V_   20000
#define M_   12800      // B_*S_
#define NPAD 20224      // 158*128
#define NBN  158        // N blocks of 128
#define NBM  100        // M blocks of 128
#define NWG2 15800      // NBN*NBM (== 8*1975)

// ws offsets (bytes) — total ~13.7 MB
#define WS_A      0u          // A1_bf16 [12800][128]      3,276,800 B
#define WS_FCW    3276800u    // W1_bf16 [20224][128]      5,177,344 B
#define WS_U      8454144u    // U [64][20224] f32         5,177,344 B
#define WS_RSUM   13631488u   // rowsum [12800] f32           51,200 B
#define WS_WTIH   13682688u   // W_ih^T [128][128] f32        65,536 B
// end 13,748,224

// scratch inside the y region of d_out (float offsets) — overwritten by final pass
#define XP_OFF    0
#define HOUT_OFF  2000000
#define PART_OFF  4000000          // [NBN][12800] partial exp-sums (2.02M floats)
#define OUTPU_OFF 256000000ll      // real output 1 (out_pu)

typedef __attribute__((ext_vector_type(8))) __bf16 bf16x8;
typedef __attribute__((ext_vector_type(4))) float  f32x4;

__device__ __forceinline__ void gll16(const void* g, void* l) {
  __builtin_amdgcn_global_load_lds(
      (const __attribute__((address_space(1))) void*)g,
      (__attribute__((address_space(3))) void*)l, 16, 0, 0);
}

// ---------------- prep: W1 bf16 (first 128 cols of fc_W) ----------------
__global__ __launch_bounds__(256)
void prep_w1(const float* __restrict__ fcw, __hip_bfloat16* __restrict__ w1) {
  int t = threadIdx.x;
  int row = blockIdx.x * 2 + (t >> 7);          // grid 10112 x 256
  int col = t & 127;
  float v = (row < V_) ? fcw[(long)row * 256 + col] : 0.f;
  w1[(long)row * 128 + col] = __float2bfloat16(v);
}

// ---------------- prep: W_ih transpose ----------------
__global__ __launch_bounds__(128)
void prep_wt(const float* __restrict__ w_ih, float* __restrict__ wt) {
  int bid = blockIdx.x, t = threadIdx.x;        // grid 128 x 128
  wt[bid * 128 + t] = w_ih[t * 128 + bid];      // wt[k][j] = W_ih[j][k]
}

// ---------------- U table: U[b][c] = p_u(b) . fcW[c,128:256] + fcb[c] ----------------
__global__ __launch_bounds__(256)
void user_k(const int* __restrict__ auser, const float* __restrict__ userW,
            const float* __restrict__ fcW, const float* __restrict__ fcb,
            float* __restrict__ U) {
  __shared__ float uw[8][128];
  int t = threadIdx.x;
  int c = blockIdx.x * 256 + t;                 // grid (79, 8)
  int b0 = blockIdx.y * 8;
  for (int i = t; i < 8 * 128; i += 256) {
    int bb = i >> 7, kk = i & 127;
    uw[bb][kk] = userW[(long)auser[b0 + bb] * 128 + kk];
  }
  __syncthreads();
  float acc[8];
#pragma unroll
  for (int bb = 0; bb < 8; ++bb) acc[bb] = 0.f;
  if (c < V_) {
    const float* w2 = fcW + (long)c * 256 + 128;
#pragma unroll 4
    for (int k = 0; k < 128; k += 4) {
      float4 wv = *(const float4*)(w2 + k);
#pragma unroll
      for (int bb = 0; bb < 8; ++bb) {
        acc[bb] = fmaf(wv.x, uw[bb][k], acc[bb]);
        acc[bb] = fmaf(wv.y, uw[bb][k + 1], acc[bb]);
        acc[bb] = fmaf(wv.z, uw[bb][k + 2], acc[bb]);
        acc[bb] = fmaf(wv.w, uw[bb][k + 3], acc[bb]);
      }
    }
    float base = fcb[c];
#pragma unroll
    for (int bb = 0; bb < 8; ++bb)
      U[(long)(b0 + bb) * NPAD + c] = base + acc[bb];
  } else {
#pragma unroll
    for (int bb = 0; bb < 8; ++bb)
      U[(long)(b0 + bb) * NPAD + c] = -1e30f;    // pad cols: exp -> 0
  }
}

// ---------------- K1: x_proj, 16 rows/block ----------------
__global__ __launch_bounds__(128)
void xproj_k(const int* __restrict__ poi, const float* __restrict__ emb,
             const float* __restrict__ wt_ih, const float* __restrict__ b_ih,
             const float* __restrict__ b_hh, float* __restrict__ xp) {
  __shared__ float xs[16][128];
  int j = threadIdx.x;
  int m0 = blockIdx.x * 16;                          // grid 800 x 128
#pragma unroll
  for (int i = 0; i < 16; ++i)
    xs[i][j] = emb[(long)poi[m0 + i] * 128 + j];
  __syncthreads();
  float bias = b_ih[j] + b_hh[j];
  float acc[16];
#pragma unroll
  for (int i = 0; i < 16; ++i) acc[i] = bias;
  for (int kq = 0; kq < 32; ++kq) {
    float w0 = wt_ih[(4 * kq + 0) * 128 + j];
    float w1 = wt_ih[(4 * kq + 1) * 128 + j];
    float w2 = wt_ih[(4 * kq + 2) * 128 + j];
    float w3 = wt_ih[(4 * kq + 3) * 128 + j];
#pragma unroll
    for (int i = 0; i < 16; ++i) {
      float4 xv = *(const float4*)&xs[i][4 * kq];
      acc[i] = fmaf(xv.x, w0, acc[i]);
      acc[i] = fmaf(xv.y, w1, acc[i]);
      acc[i] = fmaf(xv.z, w2, acc[i]);
      acc[i] = fmaf(xv.w, w3, acc[i]);
    }
  }
#pragma unroll
  for (int i = 0; i < 16; ++i)
    xp[(long)(m0 + i) * 128 + j] = acc[i];
}

// ---------------- K2: sequential RNN (b128 LDS reads, 4 chains) ----------------
__global__ __launch_bounds__(128)
void rnn_k(const float* __restrict__ xp, const float* __restrict__ w_hh,
           float* __restrict__ hout) {
  int b = blockIdx.x, j = threadIdx.x;               // grid 64 x 128
  float w[128];
#pragma unroll
  for (int k = 0; k < 128; ++k) w[k] = w_hh[j * 128 + k];
  __shared__ float hs[2][128];
  hs[0][j] = 0.f;
  __syncthreads();
  int cur = 0;
  for (int t = 0; t < S_; ++t) {
    float x0 = xp[((long)b * S_ + t) * 128 + j];
    const float4* hp4 = (const float4*)hs[cur];
    float a0 = 0.f, a1 = 0.f, a2 = 0.f, a3 = 0.f;
#pragma unroll
    for (int k = 0; k < 8; ++k) {
      float4 v0 = hp4[k], v1 = hp4[k + 8], v2 = hp4[k + 16], v3 = hp4[k + 24];
      a0 = fmaf(v0.x, w[4 * k + 0], a0); a0 = fmaf(v0.y, w[4 * k + 1], a0);
      a0 = fmaf(v0.z, w[4 * k + 2], a0); a0 = fmaf(v0.w, w[4 * k + 3], a0);
      a1 = fmaf(v1.x, w[32 + 4 * k + 0], a1); a1 = fmaf(v1.y, w[32 + 4 * k + 1], a1);
      a1 = fmaf(v1.z, w[32 + 4 * k + 2], a1); a1 = fmaf(v1.w, w[32 + 4 * k + 3], a1);
      a2 = fmaf(v2.x, w[64 + 4 * k + 0], a2); a2 = fmaf(v2.y, w[64 + 4 * k + 1], a2);
      a2 = fmaf(v2.z, w[64 + 4 * k + 2], a2); a2 = fmaf(v2.w, w[64 + 4 * k + 3], a2);
      a3 = fmaf(v3.x, w[96 + 4 * k + 0], a3); a3 = fmaf(v3.y, w[96 + 4 * k + 1], a3);
      a3 = fmaf(v3.z, w[96 + 4 * k + 2], a3); a3 = fmaf(v3.w, w[96 + 4 * k + 3], a3);
    }
    float hn = tanhf(x0 + ((a0 + a1) + (a2 + a3)));
    hs[cur ^ 1][j] = hn;
    hout[((long)b * S_ + t) * 128 + j] = hn;
    cur ^= 1;
    __syncthreads();
  }
}

// ---------------- K3: decay attention + out_pu + A1 bf16 ----------------
__global__ __launch_bounds__(128)
void attn_k(const float* __restrict__ ts, const float* __restrict__ loc,
            const float* __restrict__ hout, const int* __restrict__ auser,
            const float* __restrict__ userW, float* __restrict__ outpu,
            __hip_bfloat16* __restrict__ Abf) {
  int i = blockIdx.x, b = blockIdx.y, h = threadIdx.x;   // grid (200,64) x 128
  __shared__ float wl[128];
  const float OMEGA = 7.27220521664304e-05f;             // 2*pi/86400
  float ti = ts[b * S_ + i];
  float lx = loc[(b * S_ + i) * 2 + 0];
  float ly = loc[(b * S_ + i) * 2 + 1];
  float acc = 0.f, sw = 0.f;
  for (int jc = 0; jc <= i; jc += 128) {
    int j = jc + h;
    float wj = 0.f;
    if (j <= i) {
      float dt = fmaxf(ti - ts[b * S_ + j], 0.f);
      float a = (cosf(dt * OMEGA) + 1.f) * 0.5f * expf(-dt * 0.01f);
      float dx = lx - loc[(b * S_ + j) * 2 + 0];
      float dy = ly - loc[(b * S_ + j) * 2 + 1];
      float dn = sqrtf(dx * dx + dy * dy);
      wj = a * expf(-dn * 100.f) + 1e-10f;
    }
    __syncthreads();
    wl[h] = wj;
    __syncthreads();
    int lim = min(128, i - jc + 1);
    const float* hb = hout + ((long)b * S_ + jc) * 128 + h;
    for (int jj = 0; jj < lim; ++jj) {
      float wv = wl[jj];
      acc = fmaf(wv, hb[(long)jj * 128], acc);
      sw += wv;
    }
  }
  float ow = acc / fmaxf(sw, 1e-10f);
  long m = (long)b * S_ + i;
  float pu = userW[(long)auser[b] * 128 + h];
  outpu[m * 256 + h]       = ow;
  outpu[m * 256 + 128 + h] = pu;
  Abf[m * 128 + h]         = __float2bfloat16(ow);   // only out_w half feeds GEMM
}

// ---------------- K4/K5: FC GEMM, K=128 one-shot, 128x128 tile, 2 blocks/CU ----
// logit(r,c) = acc(r,c) + U[r/200][c];  PASS0: rowsum partials;  PASS1: y = exp/rowsum
template <int PASS>
__global__ __launch_bounds__(512, 4)
void gemm_fc(const __hip_bfloat16* __restrict__ A,    // [12800][128]
             const __hip_bfloat16* __restrict__ Bw,   // [20224][128]
             const float* __restrict__ Ut,            // [64][20224]
             const float* __restrict__ rowsum,        // [12800] (PASS 1)
             float* __restrict__ part,                 // [NBN][12800] (PASS 0)
             float* __restrict__ y) {                  // [12800][20000] (PASS 1)
  __shared__ __align__(16) char smem[65536];     // As 32K | Bs 32K ; lbuf reuses all
  __shared__ float rsum4[4][128];
  char* AsB = smem;
  char* BsB = smem + 32768;
  float* lbuf = (float*)smem;                    // [128][128] f32 (PASS 1 epilogue)

  const int tid  = threadIdx.x;
  const int lane = tid & 63;
  const int wid  = tid >> 6;               // 0..7
  const int wr = wid >> 2, wc = wid & 3;   // 2(M) x 4(N); wave tile 64x32
  const int g = lane >> 4, lr = lane & 15;

  // bijective XCD swizzle: 15800 = 8*1975 exactly
  const int orig = blockIdx.x;
  const int nid = (orig & 7) * (NWG2 / 8) + (orig >> 3);
  const int bn = nid / NBM, bm = nid % NBM;
  const long brow = (long)bm * 128, bcol = (long)bn * 128;

  const char* Ab = (const char*)A + brow * 256;   // row stride 128*2B
  const char* Bb = (const char*)Bw + bcol * 256;

  // one-shot stage: 32 KB A + 32 KB B. LDS dest linear; global src pre-swizzled
  // (w ^= row&7 on 16B units) so swizzled ds_reads are conflict-free.
#pragma unroll
  for (int i = 0; i < 4; ++i) {
    int ci = i * 512 + tid;                  // 0..2047 16B-chunks
    int row = ci >> 4;                        // 0..127
    int w = (ci & 15) ^ (row & 7);
    long src = (long)row * 256 + (long)w * 16;
    gll16(Ab + src, AsB + (long)ci * 16);
    gll16(Bb + src, BsB + (long)ci * 16);
  }
  __syncthreads();                            // vmcnt(0): tiles resident

  f32x4 acc[4][2];
#pragma unroll
  for (int mi = 0; mi < 4; ++mi)
#pragma unroll
    for (int ni = 0; ni < 2; ++ni) acc[mi][ni] = (f32x4)(0.f);

#pragma unroll
  for (int kk = 0; kk < 4; ++kk) {
    bf16x8 af[4], bfr[2];
#pragma unroll
    for (int mi = 0; mi < 4; ++mi) {
      int row = wr * 64 + mi * 16 + lr;
      int w = ((kk << 2) | g) ^ (row & 7);
      af[mi] = *(const bf16x8*)(AsB + row * 256 + w * 16);
    }
#pragma unroll
    for (int ni = 0; ni < 2; ++ni) {
      int row = wc * 32 + ni * 16 + lr;
      int w = ((kk << 2) | g) ^ (row & 7);
      bfr[ni] = *(const bf16x8*)(BsB + row * 256 + w * 16);
    }
#pragma unroll
    for (int mi = 0; mi < 4; ++mi)
#pragma unroll
      for (int ni = 0; ni < 2; ++ni)
        acc[mi][ni] = __builtin_amdgcn_mfma_f32_16x16x32_bf16(af[mi], bfr[ni], acc[mi][ni], 0, 0, 0);
  }

  if (PASS == 0) {
#pragma unroll
    for (int mi = 0; mi < 4; ++mi) {
#pragma unroll
      for (int r = 0; r < 4; ++r) {
        long row = brow + wr * 64 + mi * 16 + g * 4 + r;
        const float* urow = Ut + (long)(row / S_) * NPAD + bcol;
        float s = 0.f;
#pragma unroll
        for (int ni = 0; ni < 2; ++ni) {
          float u = urow[wc * 32 + ni * 16 + lr];
          s += __expf(acc[mi][ni][r] + u);
        }
#pragma unroll
        for (int off = 1; off < 16; off <<= 1) s += __shfl_xor(s, off);
        if (lr == 0) rsum4[wc][wr * 64 + mi * 16 + g * 4 + r] = s;
      }
    }
    __syncthreads();
    if (tid < 128)
      part[(long)bn * M_ + brow + tid] =
          rsum4[0][tid] + rsum4[1][tid] + rsum4[2][tid] + rsum4[3][tid];
  } else {
    if (bcol >= V_) return;                   // fully-OOB N panel (bn==157)
    const bool full = (bcol + 128 <= V_);
    __syncthreads();                           // As/Bs dead
#pragma unroll
    for (int mi = 0; mi < 4; ++mi) {
#pragma unroll
      for (int r = 0; r < 4; ++r) {
        int lrow = wr * 64 + mi * 16 + g * 4 + r;   // 0..127
        long row = brow + lrow;
        const float* urow = Ut + (long)(row / S_) * NPAD + bcol;
        float inv = 1.0f / rowsum[row];
        int key = ((lrow >> 2) & 3) << 2;           // bank swizzle (g-safe)
#pragma unroll
        for (int ni = 0; ni < 2; ++ni) {
          int lcol = wc * 32 + ni * 16 + lr;
          lbuf[lrow * 128 + (lcol ^ key)] = __expf(acc[mi][ni][r] + urow[lcol]) * inv;
        }
      }
    }
    __syncthreads();
    if (full) {
#pragma unroll
      for (int it = 0; it < 8; ++it) {
        int idx = it * 512 + tid;             // 0..4095 float4 slots
        int lrow = idx >> 5, c4 = idx & 31;
        int key = ((lrow >> 2) & 3) << 2;
        f32x4 v = *(const f32x4*)(lbuf + lrow * 128 + ((c4 * 4) ^ key));
        __builtin_nontemporal_store(v,
            (f32x4*)(y + (brow + lrow) * (long)V_ + bcol + c4 * 4));
      }
    } else {
#pragma unroll
      for (int it = 0; it < 8; ++it) {
        int idx = it * 512 + tid;
        int lrow = idx >> 5, c4 = idx & 31;
        int key = ((lrow >> 2) & 3) << 2;
        const float* src = lbuf + lrow * 128 + ((c4 * 4) ^ key);
        long row = brow + lrow;
#pragma unroll
        for (int e = 0; e < 4; ++e) {
          int col = (int)bcol + c4 * 4 + e;
          if (col < V_) y[row * (long)V_ + col] = src[e];
        }
      }
    }
  }
}

__global__ void reduce_rows(const float* __restrict__ part, float* __restrict__ rowsum) {
  int m = blockIdx.x * 256 + threadIdx.x;            // grid 50 x 256
  if (m < M_) {
    float s = 0.f;
    for (int bn = 0; bn < NBN; ++bn) s += part[(long)bn * M_ + m];
    rowsum[m] = fmaxf(s, 1e-30f);
  }
}

// ---------------- launcher ----------------
extern "C" void kernel_launch(void* const* d_in, const int* in_sizes, int n_in,
                              void* d_out, int out_size, void* d_ws, size_t ws_size,
                              hipStream_t stream) {
  const int*   poi   = (const int*)d_in[0];
  // d_in[1] = lengths (all == S, unused)
  const float* ts    = (const float*)d_in[2];
  const float* loc   = (const float*)d_in[3];
  const int*   auser = (const int*)d_in[4];
  const float* embW  = (const float*)d_in[5];
  const float* userW = (const float*)d_in[6];
  const float* w_ih  = (const float*)d_in[7];
  const float* w_hh  = (const float*)d_in[8];
  const float* b_ih  = (const float*)d_in[9];
  const float* b_hh  = (const float*)d_in[10];
  const float* fcW   = (const float*)d_in[11];
  const float* fcb   = (const float*)d_in[12];

  float* out = (float*)d_out;
  char*  ws  = (char*)d_ws;
  __hip_bfloat16* Abf    = (__hip_bfloat16*)(ws + WS_A);
  __hip_bfloat16* w1b    = (__hip_bfloat16*)(ws + WS_FCW);
  float*          Ut     = (float*)(ws + WS_U);
  float*          rowsum = (float*)(ws + WS_RSUM);
  float*          wt_ih  = (float*)(ws + WS_WTIH);

  float* xp    = out + XP_OFF;     // scratch inside y region (overwritten by pass 1)
  float* hout  = out + HOUT_OFF;
  float* part  = out + PART_OFF;
  float* outpu = out + OUTPU_OFF;  // real output 1

  prep_w1<<<dim3(NPAD / 2), dim3(256), 0, stream>>>(fcW, w1b);
  prep_wt<<<dim3(128), dim3(128), 0, stream>>>(w_ih, wt_ih);
  user_k<<<dim3(NPAD / 256, 8), dim3(256), 0, stream>>>(auser, userW, fcW, fcb, Ut);
  xproj_k<<<dim3(M_ / 16), dim3(128), 0, stream>>>(poi, embW, wt_ih, b_ih, b_hh, xp);
  rnn_k<<<dim3(B_), dim3(128), 0, stream>>>(xp, w_hh, hout);
  attn_k<<<dim3(S_, B_), dim3(128), 0, stream>>>(ts, loc, hout, auser, userW, outpu, Abf);
  gemm_fc<0><<<dim3(NWG2), dim3(512), 0, stream>>>(Abf, w1b, Ut, nullptr, part, nullptr);
  reduce_rows<<<dim3(50), dim3(256), 0, stream>>>(part, rowsum);
  gemm_fc<1><<<dim3(NWG2), dim3(512), 0, stream>>>(Abf, w1b, Ut, rowsum, nullptr, out);
}